// Round 10
// baseline (750.850 us; speedup 1.0000x reference)
//
#include <hip/hip_runtime.h>
#include <math.h>

#define N_NODES 100000
#define N_EDGES 600000
#define D 128
#define REL 9
#define NG 64
#define NK9 (N_NODES * REL)

typedef float f32x4 __attribute__((ext_vector_type(4)));
typedef _Float16 f16x8 __attribute__((ext_vector_type(8)));
typedef _Float16 h16x2 __attribute__((ext_vector_type(2)));

__device__ __forceinline__ ushort f2h(float x) {
    union { _Float16 h; ushort u; } c; c.h = (_Float16)x; return c.u;
}
__device__ __forceinline__ float h2f(ushort u) {
    union { ushort u; _Float16 h; } c; c.u = u; return (float)c.h;
}

// async global->LDS, 16 B per lane; dest = lds base (wave-uniform) + lane*16
__device__ __forceinline__ void ld16(const ushort* g, ushort* l) {
    __builtin_amdgcn_global_load_lds(
        (const __attribute__((address_space(1))) unsigned int*)g,
        (__attribute__((address_space(3))) unsigned int*)l, 16, 0, 0);
}

__device__ __forceinline__ int lbound(const int* __restrict__ a, int n, int key) {
    int lo = 0, hi = n;
    while (lo < hi) { int mid = (lo + hi) >> 1; if (a[mid] < key) lo = mid + 1; else hi = mid; }
    return lo;
}

// ------------------------------------------------------------ edge sorting by (dst, etype)
__global__ void hist9_kernel(const int* __restrict__ dst, const int* __restrict__ ety,
                             int* __restrict__ cnt9) {
    int e = blockIdx.x * 256 + threadIdx.x;
    if (e < N_EDGES) atomicAdd(&cnt9[dst[e] * REL + ety[e]], 1);
}

// 8 elements per thread -> 8192 per block; NK9=900000 -> 110 blocks (fits scan2's 128)
__global__ void scan1_8(const int* __restrict__ cnt, int* __restrict__ excl,
                        int* __restrict__ bsum, int n) {
    __shared__ int s[1024];
    int tid = threadIdx.x;
    int base = blockIdx.x * 8192 + tid * 8;
    int v[8]; int sum = 0;
#pragma unroll
    for (int j = 0; j < 8; ++j) { v[j] = (base + j < n) ? cnt[base + j] : 0; sum += v[j]; }
    s[tid] = sum;
    __syncthreads();
    for (int off = 1; off < 1024; off <<= 1) {
        int t = (tid >= off) ? s[tid - off] : 0;
        __syncthreads();
        s[tid] += t;
        __syncthreads();
    }
    int run = s[tid] - sum;
#pragma unroll
    for (int j = 0; j < 8; ++j) { if (base + j < n) excl[base + j] = run; run += v[j]; }
    if (tid == 1023) bsum[blockIdx.x] = s[1023];
}

__global__ void scan2_kernel(int* __restrict__ bsum, int nb) {
    __shared__ int s[128];
    int tid = threadIdx.x;
    int v = (tid < nb) ? bsum[tid] : 0;
    s[tid] = v;
    __syncthreads();
    for (int off = 1; off < 128; off <<= 1) {
        int t = (tid >= off) ? s[tid - off] : 0;
        __syncthreads();
        s[tid] += t;
        __syncthreads();
    }
    if (tid < nb) bsum[tid] = s[tid] - v;
}

__global__ void scan3_8(int* __restrict__ excl, const int* __restrict__ bsum, int n, int total) {
    int base = blockIdx.x * 8192 + threadIdx.x * 8;
    int add = bsum[blockIdx.x];
#pragma unroll
    for (int j = 0; j < 8; ++j) if (base + j < n) excl[base + j] += add;
    if (blockIdx.x == 0 && threadIdx.x == 0) excl[n] = total;  // sentinel
}

__global__ void scatter9_kernel(const int* __restrict__ src, const int* __restrict__ dst,
                                const int* __restrict__ ety, const int* __restrict__ rstart,
                                int* __restrict__ cur9, int* __restrict__ ssrc,
                                int* __restrict__ setp) {
    int e = blockIdx.x * 256 + threadIdx.x;
    if (e < N_EDGES) {
        int t = ety[e];
        int key = dst[e] * REL + t;
        int pos = rstart[key] + atomicAdd(&cur9[key], 1);
        ssrc[pos] = src[e];
        setp[pos] = t;
    }
}

// ------------------------------------------------------------- graph norm (moment form)
// Round 8 form (proven): float4 loads + 8 row-phases + per-block LDS reduction,
// ONE atomic pair per (group, channel, block).
__global__ __launch_bounds__(256)
void gn_stats(const float* __restrict__ x, const int* __restrict__ seg,
              float* __restrict__ gsum, float* __restrict__ gsumsq) {
    __shared__ float redS[8][128];
    __shared__ float redQ[8][128];
    int t = threadIdx.x;
    int c4 = (t & 31) * 4;           // 32 threads span 128 channels (float4 each)
    int rr = t >> 5;                 // 8 row-phases in flight
    int n0 = blockIdx.x * 128;
    int nend = min(n0 + 128, N_NODES);
    int len = nend - n0;
    int gfirst = seg[n0];
    int glast = seg[nend - 1];
    for (int g = gfirst; g <= glast; ++g) {
        int lo = (g == gfirst) ? n0 : n0 + lbound(seg + n0, len, g);
        int hi = (g == glast) ? nend : n0 + lbound(seg + n0, len, g + 1);
        float s0 = 0.f, s1 = 0.f, s2 = 0.f, s3 = 0.f;
        float q0 = 0.f, q1 = 0.f, q2 = 0.f, q3 = 0.f;
        for (int n = lo + rr; n < hi; n += 8) {
            float4 v = *(const float4*)&x[(size_t)n * D + c4];
            s0 += v.x; q0 += v.x * v.x;
            s1 += v.y; q1 += v.y * v.y;
            s2 += v.z; q2 += v.z * v.z;
            s3 += v.w; q3 += v.w * v.w;
        }
        redS[rr][c4 + 0] = s0; redS[rr][c4 + 1] = s1;
        redS[rr][c4 + 2] = s2; redS[rr][c4 + 3] = s3;
        redQ[rr][c4 + 0] = q0; redQ[rr][c4 + 1] = q1;
        redQ[rr][c4 + 2] = q2; redQ[rr][c4 + 3] = q3;
        __syncthreads();
        if (t < 128) {
            float ts = 0.f, tq = 0.f;
#pragma unroll
            for (int ph = 0; ph < 8; ++ph) { ts += redS[ph][t]; tq += redQ[ph][t]; }
            atomicAdd(&gsum[g * D + t], ts);
            atomicAdd(&gsumsq[g * D + t], tq);
        }
        __syncthreads();
    }
}

__global__ __launch_bounds__(256)
void gn_stats_h(const ushort* __restrict__ x, const int* __restrict__ seg,
                float* __restrict__ gsum, float* __restrict__ gsumsq) {
    __shared__ float redS[8][128];
    __shared__ float redQ[8][128];
    int t = threadIdx.x;
    int c4 = (t & 31) * 4;
    int rr = t >> 5;
    int n0 = blockIdx.x * 128;
    int nend = min(n0 + 128, N_NODES);
    int len = nend - n0;
    int gfirst = seg[n0];
    int glast = seg[nend - 1];
    for (int g = gfirst; g <= glast; ++g) {
        int lo = (g == gfirst) ? n0 : n0 + lbound(seg + n0, len, g);
        int hi = (g == glast) ? nend : n0 + lbound(seg + n0, len, g + 1);
        float s0 = 0.f, s1 = 0.f, s2 = 0.f, s3 = 0.f;
        float q0 = 0.f, q1 = 0.f, q2 = 0.f, q3 = 0.f;
        for (int n = lo + rr; n < hi; n += 8) {
            ushort4 u = *(const ushort4*)&x[(size_t)n * D + c4];
            float v0 = h2f(u.x), v1 = h2f(u.y), v2 = h2f(u.z), v3 = h2f(u.w);
            s0 += v0; q0 += v0 * v0;
            s1 += v1; q1 += v1 * v1;
            s2 += v2; q2 += v2 * v2;
            s3 += v3; q3 += v3 * v3;
        }
        redS[rr][c4 + 0] = s0; redS[rr][c4 + 1] = s1;
        redS[rr][c4 + 2] = s2; redS[rr][c4 + 3] = s3;
        redQ[rr][c4 + 0] = q0; redQ[rr][c4 + 1] = q1;
        redQ[rr][c4 + 2] = q2; redQ[rr][c4 + 3] = q3;
        __syncthreads();
        if (t < 128) {
            float ts = 0.f, tq = 0.f;
#pragma unroll
            for (int ph = 0; ph < 8; ++ph) { ts += redS[ph][t]; tq += redQ[ph][t]; }
            atomicAdd(&gsum[g * D + t], ts);
            atomicAdd(&gsumsq[g * D + t], tq);
        }
        __syncthreads();
    }
}

__global__ void gn_final(const float* __restrict__ gsum, const float* __restrict__ gsumsq,
                         const int* __restrict__ seg, const float* __restrict__ w,
                         const float* __restrict__ b, const float* __restrict__ ms,
                         float* __restrict__ sc, float* __restrict__ off) {
    int g = blockIdx.x, ch = threadIdx.x;
    int lo = lbound(seg, N_NODES, g), hi = lbound(seg, N_NODES, g + 1);
    float cnt = (float)max(hi - lo, 1);
    float mean = gsum[g * D + ch] / cnt;
    float mm = mean * ms[ch];
    float var = gsumsq[g * D + ch] / cnt - 2.f * mm * mean + mm * mm;
    float rstd = rsqrtf(var + 1e-6f);
    float s = w[ch] * rstd;
    sc[g * D + ch] = s;
    off[g * D + ch] = b[ch] - s * mm;
}

__global__ __launch_bounds__(256)
void gn_apply(const float* __restrict__ x, const int* __restrict__ seg,
              const float* __restrict__ sc, const float* __restrict__ off,
              ushort* __restrict__ outhf) {
    int t = blockIdx.x * 256 + threadIdx.x;
    int n = t >> 6;
    if (n >= N_NODES) return;
    int ch = (t & 63) * 2;
    int g = seg[n];
    float2 xv = *(const float2*)&x[(size_t)n * D + ch];
    float2 s2 = *(const float2*)&sc[g * D + ch];
    float2 o2 = *(const float2*)&off[g * D + ch];
    ushort2 o;
    o.x = f2h(s2.x * xv.x + o2.x);
    o.y = f2h(s2.y * xv.y + o2.y);
    *(ushort2*)&outhf[(size_t)n * D + ch] = o;
}

__global__ __launch_bounds__(256)
void gn_apply_h(const ushort* __restrict__ x, const int* __restrict__ seg,
                const float* __restrict__ sc, const float* __restrict__ off,
                ushort* __restrict__ outhf) {
    int t = blockIdx.x * 256 + threadIdx.x;
    int n = t >> 6;
    if (n >= N_NODES) return;
    int ch = (t & 63) * 2;
    int g = seg[n];
    ushort2 xv = *(const ushort2*)&x[(size_t)n * D + ch];
    float2 s2 = *(const float2*)&sc[g * D + ch];
    float2 o2 = *(const float2*)&off[g * D + ch];
    ushort2 o;
    o.x = f2h(s2.x * h2f(xv.x) + o2.x);
    o.y = f2h(s2.y * h2f(xv.y) + o2.y);
    *(ushort2*)&outhf[(size_t)n * D + ch] = o;
}

// ------------------------- combined QKV weight build (fp16, transposed), all 3 projections
__global__ void build_bt_qkv3(const float* __restrict__ c0, const float* __restrict__ c1,
                              const float* __restrict__ c2, const float* __restrict__ b0,
                              const float* __restrict__ b1, const float* __restrict__ b2,
                              const float* __restrict__ l0, const float* __restrict__ l1,
                              const float* __restrict__ l2, const float* __restrict__ i0,
                              const float* __restrict__ i1, const float* __restrict__ i2,
                              ushort* __restrict__ Btqkv, float* __restrict__ biasq) {
    int pj = blockIdx.y;
    const float* coeff  = pj == 0 ? c0 : (pj == 1 ? c1 : c2);
    const float* basis  = pj == 0 ? b0 : (pj == 1 ? b1 : b2);
    const float* loop_w = pj == 0 ? l0 : (pj == 1 ? l1 : l2);
    const float* bin    = pj == 0 ? i0 : (pj == 1 ? i1 : i2);
    ushort* Bt = Btqkv + (size_t)pj * 128 * 1280;
    int t = blockIdx.x * 256 + threadIdx.x;
    if (t < 128) biasq[pj * 128 + t] = bin[t];
    if (t >= 128 * 1280) return;
    int o = t / 1280;
    int k = t - o * 1280;
    float v;
    if (k < 128) {
        v = loop_w[k * 128 + o];
    } else {
        int kk = k - 128;
        int r = kk >> 7, i = kk & 127;
        v = 0.f;
#pragma unroll
        for (int b = 0; b < REL; ++b)
            v += coeff[r * REL + b] * basis[((size_t)b * 128 + i) * 128 + o];
    }
    Bt[(size_t)o * 1280 + k] = f2h(v);
}

// single launch for o_w / ffn1 / ffn2 transposed fp16 weights
__global__ void transpose_cast3(const float* __restrict__ o_w, ushort* __restrict__ Bto,
                                const float* __restrict__ f1, ushort* __restrict__ Btf1,
                                const float* __restrict__ f2, ushort* __restrict__ Btf2) {
    int t = blockIdx.x * 256 + threadIdx.x;
    if (t < 16384) {                 // o_w: I=128, O=128
        int n = t >> 7, k = t & 127;
        Bto[(size_t)n * 128 + k] = f2h(o_w[(size_t)k * 128 + n]);
    } else if (t < 49152) {          // ffn1: I=128, O=256
        int u = t - 16384;
        int n = u >> 7, k = u & 127;
        Btf1[(size_t)n * 128 + k] = f2h(f1[(size_t)k * 256 + n]);
    } else if (t < 81920) {          // ffn2: I=256, O=128
        int u = t - 49152;
        int n = u >> 8, k = u & 255;
        Btf2[(size_t)n * 256 + k] = f2h(f2[(size_t)k * 128 + n]);
    }
}

// ----------------------------------------- per-relation gathered sums -> Ab rows (fp16, 1152)
// half2 packed accumulation; 4-edge unroll (proven r9).
__global__ __launch_bounds__(256)
void s_pass(const ushort* __restrict__ hnhf, const int* __restrict__ ssrc,
            const int* __restrict__ setp, const int* __restrict__ rstart,
            ushort* __restrict__ Ab, int c0, int c1) {
    int n = c0 + ((blockIdx.x * 256 + threadIdx.x) >> 6);
    if (n >= c1) return;
    int lane = threadIdx.x & 63;
    int e0 = rstart[n * REL], e1 = rstart[n * REL + REL];
    h16x2 a0 = (h16x2)0, a1 = (h16x2)0, a2 = (h16x2)0, a3 = (h16x2)0, a4 = (h16x2)0;
    h16x2 a5 = (h16x2)0, a6 = (h16x2)0, a7 = (h16x2)0, a8 = (h16x2)0;
#define ACC(rr, hv) switch (rr) { \
        case 0: a0 += hv; break; case 1: a1 += hv; break; case 2: a2 += hv; break; \
        case 3: a3 += hv; break; case 4: a4 += hv; break; case 5: a5 += hv; break; \
        case 6: a6 += hv; break; case 7: a7 += hv; break; default: a8 += hv; break; }
    int e = e0;
    for (; e + 4 <= e1; e += 4) {
        int s0 = ssrc[e], s1 = ssrc[e + 1], s2 = ssrc[e + 2], s3 = ssrc[e + 3];
        int r0 = __builtin_amdgcn_readfirstlane(setp[e]);
        int r1 = __builtin_amdgcn_readfirstlane(setp[e + 1]);
        int r2 = __builtin_amdgcn_readfirstlane(setp[e + 2]);
        int r3 = __builtin_amdgcn_readfirstlane(setp[e + 3]);
        h16x2 hv0 = *(const h16x2*)&hnhf[(size_t)s0 * D + 2 * lane];
        h16x2 hv1 = *(const h16x2*)&hnhf[(size_t)s1 * D + 2 * lane];
        h16x2 hv2 = *(const h16x2*)&hnhf[(size_t)s2 * D + 2 * lane];
        h16x2 hv3 = *(const h16x2*)&hnhf[(size_t)s3 * D + 2 * lane];
        ACC(r0, hv0)
        ACC(r1, hv1)
        ACC(r2, hv2)
        ACC(r3, hv3)
    }
    for (; e < e1; ++e) {
        int s0 = ssrc[e];
        int r0 = __builtin_amdgcn_readfirstlane(setp[e]);
        h16x2 hv0 = *(const h16x2*)&hnhf[(size_t)s0 * D + 2 * lane];
        ACC(r0, hv0)
    }
#undef ACC
    ushort* arow = Ab + (size_t)(n - c0) * 1152;
#define ST(r) *(h16x2*)&arow[r * 128 + 2 * lane] = a##r;
    ST(0) ST(1) ST(2) ST(3) ST(4) ST(5) ST(6) ST(7) ST(8)
#undef ST
}

// ---------------------------------------------------- QKV MFMA GEMM, full 384-col block
// Block = 128 rows x ALL 384 cols (A read ONCE).
// 512 threads, 8 waves (2 row-halves x 4 col-quarters), acc[4][6]; LDS 64 KB (2 blk/CU).
// K: 0..127 from hnhf (lda 128), 128..1279 from Ab (lda 1152, col k-128).
__global__ __launch_bounds__(512)
void mfma_gemm384(const ushort* __restrict__ A1, const ushort* __restrict__ Ab, int M,
                  const ushort* __restrict__ Bt, const float* __restrict__ bias,
                  ushort* __restrict__ Cout) {
    __shared__ ushort As[128 * 64];
    __shared__ ushort Bs[384 * 64];
    const int tid = threadIdx.x;
    const int lane = tid & 63;
    const int wave = tid >> 6;               // 0..7
    const int wm = wave & 1, wn = wave >> 1; // 2 row-halves x 4 col-quarters
    const int quad = lane >> 4, l16 = lane & 15;
    const int row0 = blockIdx.x * 128;

    const ushort* sA1[2];
    const ushort* sA2[2];
#pragma unroll
    for (int i = 0; i < 2; ++i) {
        int rs = (wave * 2 + i) * 8 + (lane >> 3);
        int kg = (lane & 7) ^ (rs & 7);
        int ra = row0 + rs; if (ra >= M) ra = M - 1;
        sA1[i] = A1 + (size_t)ra * 128 + kg * 8;
        sA2[i] = Ab + (size_t)ra * 1152 + kg * 8;
    }
    const ushort* sB[6];
#pragma unroll
    for (int i = 0; i < 6; ++i) {
        int rs = (wave * 6 + i) * 8 + (lane >> 3);
        int kg = (lane & 7) ^ (rs & 7);
        sB[i] = Bt + (size_t)rs * 1280 + kg * 8;
    }

    f32x4 acc[4][6];
#pragma unroll
    for (int i = 0; i < 4; ++i)
#pragma unroll
        for (int j = 0; j < 6; ++j) acc[i][j] = (f32x4){0.f, 0.f, 0.f, 0.f};

    for (int kc = 0; kc < 1280; kc += 64) {
#pragma unroll
        for (int i = 0; i < 6; ++i) ld16(sB[i] + kc, &Bs[(wave * 6 + i) * 512]);
#pragma unroll
        for (int i = 0; i < 2; ++i) {
            const ushort* as = (kc < 128) ? (sA1[i] + kc) : (sA2[i] + (kc - 128));
            ld16(as, &As[(wave * 2 + i) * 512]);
        }
        __syncthreads();
#pragma unroll
        for (int h = 0; h < 2; ++h) {
            f16x8 af[4], bf[6];
#pragma unroll
            for (int i = 0; i < 4; ++i) {
                int r = wm * 64 + i * 16 + l16;
                af[i] = *(const f16x8*)&As[r * 64 + (((h * 4 + quad) ^ (r & 7)) * 8)];
            }
#pragma unroll
            for (int j = 0; j < 6; ++j) {
                int c = wn * 96 + j * 16 + l16;
                bf[j] = *(const f16x8*)&Bs[c * 64 + (((h * 4 + quad) ^ (c & 7)) * 8)];
            }
#pragma unroll
            for (int i = 0; i < 4; ++i)
#pragma unroll
                for (int j = 0; j < 6; ++j)
                    acc[i][j] = __builtin_amdgcn_mfma_f32_16x16x32_f16(af[i], bf[j], acc[i][j], 0, 0, 0);
        }
        __syncthreads();
    }

#pragma unroll
    for (int i = 0; i < 4; ++i) {
        int gr0 = wm * 64 + i * 16 + quad * 4 + row0;
#pragma unroll
        for (int r = 0; r < 4; ++r) {
            int gr = gr0 + r;
            if (gr >= M) continue;
#pragma unroll
            for (int j = 0; j < 6; ++j) {
                int gcol = wn * 96 + j * 16 + l16;
                float v = acc[i][j][r] + bias[gcol];
                v = fmaxf(v, 0.f);
                Cout[(size_t)gr * 384 + gcol] = f2h(v);
            }
        }
    }
}

// ------------------------------------------------ fp16 MFMA GEMM + fused row LayerNorm
// (o-projection + ln1; 256 threads, 4 waves)
template<bool F16OUT>
__global__ __launch_bounds__(256, 3)
void mfma_gemm_ln(const ushort* __restrict__ A, int lda, int M,
                  const ushort* __restrict__ Bt, int K,
                  const float* __restrict__ bias, const float* __restrict__ lng,
                  const float* __restrict__ lnb, void* __restrict__ Cout) {
    __shared__ ushort As[128 * 64];
    __shared__ ushort Bs[128 * 64];
    __shared__ float rsum[2][128];
    __shared__ float rsq[2][128];
    const int tid = threadIdx.x;
    const int lane = tid & 63;
    const int wave = tid >> 6;
    const int wm = wave & 1, wn = wave >> 1;
    const int quad = lane >> 4, l16 = lane & 15;
    const int row0 = blockIdx.y * 128;

    const ushort* sA[4];
    const ushort* sB[4];
#pragma unroll
    for (int i = 0; i < 4; ++i) {
        int rs = (wave * 4 + i) * 8 + (lane >> 3);
        int kg = (lane & 7) ^ (rs & 7);
        int ra = row0 + rs; if (ra >= M) ra = M - 1;
        sA[i] = A + (size_t)ra * lda + kg * 8;
        sB[i] = Bt + (size_t)rs * K + kg * 8;
    }

    f32x4 acc[4][4];
#pragma unroll
    for (int i = 0; i < 4; ++i)
#pragma unroll
        for (int j = 0; j < 4; ++j) acc[i][j] = (f32x4){0.f, 0.f, 0.f, 0.f};

    for (int kc = 0; kc < K; kc += 64) {
#pragma unroll
        for (int i = 0; i < 4; ++i) {
            ld16(sA[i] + kc, &As[(wave * 4 + i) * 512]);
            ld16(sB[i] + kc, &Bs[(wave * 4 + i) * 512]);
        }
        __syncthreads();
#pragma unroll
        for (int h = 0; h < 2; ++h) {
            f16x8 af[4], bf[4];
#pragma unroll
            for (int i = 0; i < 4; ++i) {
                int r = wm * 64 + i * 16 + l16;
                af[i] = *(const f16x8*)&As[r * 64 + (((h * 4 + quad) ^ (r & 7)) * 8)];
                int c = wn * 64 + i * 16 + l16;
                bf[i] = *(const f16x8*)&Bs[c * 64 + (((h * 4 + quad) ^ (c & 7)) * 8)];
            }
#pragma unroll
            for (int i = 0; i < 4; ++i)
#pragma unroll
                for (int j = 0; j < 4; ++j)
                    acc[i][j] = __builtin_amdgcn_mfma_f32_16x16x32_f16(af[i], bf[j], acc[i][j], 0, 0, 0);
        }
        __syncthreads();
    }

#pragma unroll
    for (int i = 0; i < 4; ++i) {
#pragma unroll
        for (int r = 0; r < 4; ++r) {
            float s = 0.f, q = 0.f;
#pragma unroll
            for (int j = 0; j < 4; ++j) {
                float v = acc[i][j][r] + bias[wn * 64 + j * 16 + l16];
                s += v; q += v * v;
            }
            s += __shfl_xor(s, 1); q += __shfl_xor(q, 1);
            s += __shfl_xor(s, 2); q += __shfl_xor(q, 2);
            s += __shfl_xor(s, 4); q += __shfl_xor(q, 4);
            s += __shfl_xor(s, 8); q += __shfl_xor(q, 8);
            if (l16 == 0) {
                int row = wm * 64 + i * 16 + quad * 4 + r;
                rsum[wn][row] = s;
                rsq[wn][row] = q;
            }
        }
    }
    __syncthreads();

#pragma unroll
    for (int i = 0; i < 4; ++i) {
#pragma unroll
        for (int r = 0; r < 4; ++r) {
            int row = wm * 64 + i * 16 + quad * 4 + r;
            int grow = row0 + row;
            if (grow >= M) continue;
            float tot = rsum[0][row] + rsum[1][row];
            float tq  = rsq[0][row] + rsq[1][row];
            float mu = tot * (1.f / 128.f);
            float var = tq * (1.f / 128.f) - mu * mu;
            float rstd = rsqrtf(var + 1e-5f);
#pragma unroll
            for (int j = 0; j < 4; ++j) {
                int gcol = wn * 64 + j * 16 + l16;
                float v = acc[i][j][r] + bias[gcol];
                float o = lng[gcol] * (v - mu) * rstd + lnb[gcol];
                if (F16OUT) ((ushort*)Cout)[(size_t)grow * 128 + gcol] = f2h(o);
                else        ((float*)Cout)[(size_t)grow * 128 + gcol] = o;
            }
        }
    }
}

// ---------------------------------------------------------------- fused FFN (round 10)
// Per 128-row block: phase 1 C1 = relu(A x B1t + b1) [128x256] kept in LDS (chunk-XOR
// swizzled exactly like the MFMA A-fragment reader expects); phase 2 C2 = C1 x B2t + b2
// with fused row-LN -> d_out fp32. Eliminates the 102 MB ffn1hf round-trip and the 2nd
// A staging pass. 512 threads, 8 waves; LDS 116 KB dynamic (1 blk/CU).
__global__ __launch_bounds__(512)
void ffn_fused(const ushort* __restrict__ A, int M,
               const ushort* __restrict__ B1t, const float* __restrict__ b1,
               const ushort* __restrict__ B2t, const float* __restrict__ b2,
               const float* __restrict__ lng, const float* __restrict__ lnb,
               float* __restrict__ Cout) {
    extern __shared__ ushort sh[];
    ushort* As   = sh;                           // 128*64
    ushort* Bs   = sh + 128 * 64;                // 256*64 (phase1) / 128*64 (phase2)
    ushort* C1s  = sh + 128 * 64 + 256 * 64;     // 128*256
    float*  rsum = (float*)(C1s + 128 * 256);    // [4][128]
    float*  rsq  = rsum + 4 * 128;
    const int tid = threadIdx.x;
    const int lane = tid & 63;
    const int wave = tid >> 6;               // 0..7
    const int quad = lane >> 4, l16 = lane & 15;
    const int row0 = blockIdx.x * 128;

    // ---------------- phase 1: 128x256, waves = 2 row-halves x 4 col-quarters (64 cols)
    {
        const int wm = wave & 1, wn = wave >> 1;
        const ushort* sA[2];
#pragma unroll
        for (int i = 0; i < 2; ++i) {
            int rs = (wave * 2 + i) * 8 + (lane >> 3);
            int kg = (lane & 7) ^ (rs & 7);
            int ra = row0 + rs; if (ra >= M) ra = M - 1;
            sA[i] = A + (size_t)ra * 128 + kg * 8;
        }
        const ushort* sB[4];
#pragma unroll
        for (int i = 0; i < 4; ++i) {
            int rs = (wave * 4 + i) * 8 + (lane >> 3);
            int kg = (lane & 7) ^ (rs & 7);
            sB[i] = B1t + (size_t)rs * 128 + kg * 8;
        }
        f32x4 acc[4][4];
#pragma unroll
        for (int i = 0; i < 4; ++i)
#pragma unroll
            for (int j = 0; j < 4; ++j) acc[i][j] = (f32x4){0.f, 0.f, 0.f, 0.f};

        for (int kc = 0; kc < 128; kc += 64) {
#pragma unroll
            for (int i = 0; i < 4; ++i) ld16(sB[i] + kc, &Bs[(wave * 4 + i) * 512]);
#pragma unroll
            for (int i = 0; i < 2; ++i) ld16(sA[i] + kc, &As[(wave * 2 + i) * 512]);
            __syncthreads();
#pragma unroll
            for (int h = 0; h < 2; ++h) {
                f16x8 af[4], bf[4];
#pragma unroll
                for (int i = 0; i < 4; ++i) {
                    int r = wm * 64 + i * 16 + l16;
                    af[i] = *(const f16x8*)&As[r * 64 + (((h * 4 + quad) ^ (r & 7)) * 8)];
                }
#pragma unroll
                for (int j = 0; j < 4; ++j) {
                    int c = wn * 64 + j * 16 + l16;
                    bf[j] = *(const f16x8*)&Bs[c * 64 + (((h * 4 + quad) ^ (c & 7)) * 8)];
                }
#pragma unroll
                for (int i = 0; i < 4; ++i)
#pragma unroll
                    for (int j = 0; j < 4; ++j)
                        acc[i][j] = __builtin_amdgcn_mfma_f32_16x16x32_f16(af[i], bf[j], acc[i][j], 0, 0, 0);
            }
            __syncthreads();
        }

        // epilogue: relu + bias, store swizzled into C1s
#pragma unroll
        for (int i = 0; i < 4; ++i) {
            int lr0 = wm * 64 + i * 16 + quad * 4;
#pragma unroll
            for (int r = 0; r < 4; ++r) {
                int row = lr0 + r;
                int rw = row & 7;
#pragma unroll
                for (int j = 0; j < 4; ++j) {
                    int cbase = j * 16 + l16;      // 0..63 within the 64-col quarter
                    int kg = cbase >> 3;
                    float v = acc[i][j][r] + b1[wn * 64 + cbase];
                    v = fmaxf(v, 0.f);
                    C1s[row * 256 + wn * 64 + ((kg ^ rw) * 8) + (cbase & 7)] = f2h(v);
                }
            }
        }
    }
    __syncthreads();

    // ---------------- phase 2: 128x128, K=256 from C1s; waves = 2 x 4 (32 cols each)
    {
        const int wm = wave & 1, wn = wave >> 1;
        const ushort* sB[2];
#pragma unroll
        for (int i = 0; i < 2; ++i) {
            int rs = (wave * 2 + i) * 8 + (lane >> 3);
            int kg = (lane & 7) ^ (rs & 7);
            sB[i] = B2t + (size_t)rs * 256 + kg * 8;
        }
        f32x4 acc[4][2];
#pragma unroll
        for (int i = 0; i < 4; ++i)
#pragma unroll
            for (int j = 0; j < 2; ++j) acc[i][j] = (f32x4){0.f, 0.f, 0.f, 0.f};

        for (int kc = 0; kc < 256; kc += 64) {
#pragma unroll
            for (int i = 0; i < 2; ++i) ld16(sB[i] + kc, &Bs[(wave * 2 + i) * 512]);
            __syncthreads();
#pragma unroll
            for (int h = 0; h < 2; ++h) {
                f16x8 af[4], bf[2];
#pragma unroll
                for (int i = 0; i < 4; ++i) {
                    int r = wm * 64 + i * 16 + l16;
                    af[i] = *(const f16x8*)&C1s[r * 256 + kc + (((h * 4 + quad) ^ (r & 7)) * 8)];
                }
#pragma unroll
                for (int j = 0; j < 2; ++j) {
                    int c = wn * 32 + j * 16 + l16;
                    bf[j] = *(const f16x8*)&Bs[c * 64 + (((h * 4 + quad) ^ (c & 7)) * 8)];
                }
#pragma unroll
                for (int i = 0; i < 4; ++i)
#pragma unroll
                    for (int j = 0; j < 2; ++j)
                        acc[i][j] = __builtin_amdgcn_mfma_f32_16x16x32_f16(af[i], bf[j], acc[i][j], 0, 0, 0);
            }
            __syncthreads();
        }

        // row-LN across 4 col-quarters
#pragma unroll
        for (int i = 0; i < 4; ++i) {
#pragma unroll
            for (int r = 0; r < 4; ++r) {
                float s = 0.f, q = 0.f;
#pragma unroll
                for (int j = 0; j < 2; ++j) {
                    float v = acc[i][j][r] + b2[wn * 32 + j * 16 + l16];
                    s += v; q += v * v;
                }
                s += __shfl_xor(s, 1); q += __shfl_xor(q, 1);
                s += __shfl_xor(s, 2); q += __shfl_xor(q, 2);
                s += __shfl_xor(s, 4); q += __shfl_xor(q, 4);
                s += __shfl_xor(s, 8); q += __shfl_xor(q, 8);
                if (l16 == 0) {
                    int row = wm * 64 + i * 16 + quad * 4 + r;
                    rsum[wn * 128 + row] = s;
                    rsq[wn * 128 + row] = q;
                }
            }
        }
        __syncthreads();

#pragma unroll
        for (int i = 0; i < 4; ++i) {
#pragma unroll
            for (int r = 0; r < 4; ++r) {
                int row = wm * 64 + i * 16 + quad * 4 + r;
                int grow = row0 + row;
                if (grow >= M) continue;
                float tot = rsum[row] + rsum[128 + row] + rsum[256 + row] + rsum[384 + row];
                float tq  = rsq[row] + rsq[128 + row] + rsq[256 + row] + rsq[384 + row];
                float mu = tot * (1.f / 128.f);
                float var = tq * (1.f / 128.f) - mu * mu;
                float rstd = rsqrtf(var + 1e-5f);
#pragma unroll
                for (int j = 0; j < 2; ++j) {
                    int gcol = wn * 32 + j * 16 + l16;
                    float v = acc[i][j][r] + b2[gcol];
                    float o = lng[gcol] * (v - mu) * rstd + lnb[gcol];
                    Cout[(size_t)grow * 128 + gcol] = o;
                }
            }
        }
    }
}

// --------------------------------------------------------------- attention
// 8-edge unroll (proven r9); don't touch further — at gather-BW plateau (~3.5 TB/s).
__global__ __launch_bounds__(256)
void attn_kernel(const ushort* __restrict__ C, const int* __restrict__ ssrc,
                 const int* __restrict__ rstart, ushort* __restrict__ attnhf) {
    int n = (blockIdx.x * 256 + threadIdx.x) >> 6;
    if (n >= N_NODES) return;
    int lane = threadIdx.x & 63;
    h16x2 qh = *(const h16x2*)&C[(size_t)n * 384 + 2 * lane];
    int e0 = rstart[n * REL], e1 = rstart[n * REL + REL];
    float wvx = 0.f, wvy = 0.f, z = 0.f;
    int e = e0;
    for (; e + 8 <= e1; e += 8) {
        int s[8];
#pragma unroll
        for (int j = 0; j < 8; ++j) s[j] = ssrc[e + j];
        h16x2 kk[8], vv[8];
#pragma unroll
        for (int j = 0; j < 8; ++j) kk[j] = *(const h16x2*)&C[(size_t)s[j] * 384 + 128 + 2 * lane];
#pragma unroll
        for (int j = 0; j < 8; ++j) vv[j] = *(const h16x2*)&C[(size_t)s[j] * 384 + 256 + 2 * lane];
        float d[8];
#pragma unroll
        for (int j = 0; j < 8; ++j) d[j] = __builtin_amdgcn_fdot2(kk[j], qh, 0.f, false);
#pragma unroll
        for (int j = 0; j < 8; ++j) d[j] += __shfl_xor(d[j], 1);
#pragma unroll
        for (int j = 0; j < 8; ++j) d[j] += __shfl_xor(d[j], 2);
#pragma unroll
        for (int j = 0; j < 8; ++j) d[j] += __shfl_xor(d[j], 4);
#pragma unroll
        for (int j = 0; j < 8; ++j) {
            float sc = __expf(fminf(fmaxf(d[j] * 0.25f, -10.f), 10.f));
            wvx += sc * (float)vv[j].x;
            wvy += sc * (float)vv[j].y;
            z += sc;
        }
    }
    for (; e + 4 <= e1; e += 4) {
        int s0 = ssrc[e], s1 = ssrc[e + 1], s2 = ssrc[e + 2], s3 = ssrc[e + 3];
        h16x2 k0 = *(const h16x2*)&C[(size_t)s0 * 384 + 128 + 2 * lane];
        h16x2 k1 = *(const h16x2*)&C[(size_t)s1 * 384 + 128 + 2 * lane];
        h16x2 k2 = *(const h16x2*)&C[(size_t)s2 * 384 + 128 + 2 * lane];
        h16x2 k3 = *(const h16x2*)&C[(size_t)s3 * 384 + 128 + 2 * lane];
        h16x2 v0 = *(const h16x2*)&C[(size_t)s0 * 384 + 256 + 2 * lane];
        h16x2 v1 = *(const h16x2*)&C[(size_t)s1 * 384 + 256 + 2 * lane];
        h16x2 v2 = *(const h16x2*)&C[(size_t)s2 * 384 + 256 + 2 * lane];
        h16x2 v3 = *(const h16x2*)&C[(size_t)s3 * 384 + 256 + 2 * lane];
        float d0 = __builtin_amdgcn_fdot2(k0, qh, 0.f, false);
        float d1 = __builtin_amdgcn_fdot2(k1, qh, 0.f, false);
        float d2 = __builtin_amdgcn_fdot2(k2, qh, 0.f, false);
        float d3 = __builtin_amdgcn_fdot2(k3, qh, 0.f, false);
        d0 += __shfl_xor(d0, 1); d1 += __shfl_xor(d1, 1);
        d2 += __shfl_xor(d2, 1); d3 += __shfl_xor(d3, 1);
        d0 += __shfl_xor(d0, 2); d1 += __shfl_xor(d1, 2);
        d2 += __shfl_xor(d2, 2); d3 += __shfl_xor(d3, 2);
        d0 += __shfl_xor(d0, 4); d1 += __shfl_xor(d1, 4);
        d2 += __shfl_xor(d2, 4); d3 += __shfl_xor(d3, 4);
        float sc0 = __expf(fminf(fmaxf(d0 * 0.25f, -10.f), 10.f));
        float sc1 = __expf(fminf(fmaxf(d1 * 0.25f, -10.f), 10.f));
        float sc2 = __expf(fminf(fmaxf(d2 * 0.25f, -10.f), 10.f));
        float sc3 = __expf(fminf(fmaxf(d3 * 0.25f, -10.f), 10.f));
        wvx += sc0 * (float)v0.x + sc1 * (float)v1.x;
        wvy += sc0 * (float)v0.y + sc1 * (float)v1.y;
        wvx += sc2 * (float)v2.x + sc3 * (float)v3.x;
        wvy += sc2 * (float)v2.y + sc3 * (float)v3.y;
        z += sc0 + sc1 + sc2 + sc3;
    }
    for (; e < e1; ++e) {
        int s0 = ssrc[e];
        h16x2 k0 = *(const h16x2*)&C[(size_t)s0 * 384 + 128 + 2 * lane];
        h16x2 v0 = *(const h16x2*)&C[(size_t)s0 * 384 + 256 + 2 * lane];
        float d0 = __builtin_amdgcn_fdot2(k0, qh, 0.f, false);
        d0 += __shfl_xor(d0, 1);
        d0 += __shfl_xor(d0, 2);
        d0 += __shfl_xor(d0, 4);
        float sc0 = __expf(fminf(fmaxf(d0 * 0.25f, -10.f), 10.f));
        wvx += sc0 * (float)v0.x;
        wvy += sc0 * (float)v0.y;
        z += sc0;
    }
    float inv = 1.f / (z + 1e-6f);
    ushort2 o;
    o.x = f2h(wvx * inv);
    o.y = f2h(wvy * inv);
    *(ushort2*)&attnhf[(size_t)n * D + 2 * lane] = o;
}

// ------------------------------------------------------------------ launch
extern "C" void kernel_launch(void* const* d_in, const int* in_sizes, int n_in,
                              void* d_out, int out_size, void* d_ws, size_t ws_size,
                              hipStream_t stream) {
    (void)in_sizes; (void)n_in; (void)out_size;
    const float* h     = (const float*)d_in[0];
    const int*   src   = (const int*)d_in[1];
    const int*   dst   = (const int*)d_in[2];
    const int*   ety   = (const int*)d_in[3];
    const int*   seg   = (const int*)d_in[4];
    const float* coeffs[3] = {(const float*)d_in[6],  (const float*)d_in[10], (const float*)d_in[14]};
    const float* bases [3] = {(const float*)d_in[7],  (const float*)d_in[11], (const float*)d_in[15]};
    const float* loops [3] = {(const float*)d_in[8],  (const float*)d_in[12], (const float*)d_in[16]};
    const float* pbias [3] = {(const float*)d_in[9],  (const float*)d_in[13], (const float*)d_in[17]};
    const float* o_w   = (const float*)d_in[18];
    const float* o_b   = (const float*)d_in[19];
    const float* gn1_w = (const float*)d_in[20];
    const float* gn1_b = (const float*)d_in[21];
    const float* gn1_ms= (const float*)d_in[22];
    const float* gn2_w = (const float*)d_in[23];
    const float* gn2_b = (const float*)d_in[24];
    const float* gn2_ms= (const float*)d_in[25];
    const float* ln1_g = (const float*)d_in[26];
    const float* ln1_b = (const float*)d_in[27];
    const float* ln2_g = (const float*)d_in[28];
    const float* ln2_b = (const float*)d_in[29];
    const float* ffn1_w= (const float*)d_in[30];
    const float* ffn1_b= (const float*)d_in[31];
    const float* ffn2_w= (const float*)d_in[32];
    const float* ffn2_b= (const float*)d_in[33];

    char* p = (char*)d_ws;
    auto take = [&](size_t bytes) { char* r = p; p += (bytes + 255) & ~(size_t)255; return r; };
    int*    cnt9   = (int*)take((size_t)NK9 * 2 * 4);   // cnt9 + cur9, single memset
    int*    cur9   = cnt9 + NK9;
    int*    rstart = (int*)take((size_t)(NK9 + 8) * 4); // +sentinel
    int*    bsum   = (int*)take(512);
    int*    ssrc   = (int*)take((size_t)N_EDGES * 4);
    int*    setp   = (int*)take((size_t)N_EDGES * 4);
    float*  gsum   = (float*)take((size_t)NG * D * 4 * 2);
    float*  gsumsq = gsum + NG * D;
    float*  gsc    = (float*)take((size_t)NG * D * 4);
    float*  goff   = (float*)take((size_t)NG * D * 4);
    ushort* Btqkv  = (ushort*)take((size_t)384 * 1280 * 2);
    float*  biasq  = (float*)take(384 * 4);
    ushort* Bto    = (ushort*)take((size_t)128 * 128 * 2);
    ushort* Btf1   = (ushort*)take((size_t)256 * 128 * 2);
    ushort* Btf2   = (ushort*)take((size_t)128 * 256 * 2);
    ushort* hnhf   = (ushort*)take((size_t)N_NODES * D * 2);     // 25.6 MB
    ushort* attnhf = (ushort*)take((size_t)N_NODES * D * 2);     // 25.6 MB
    ushort* h1hf   = (ushort*)take((size_t)N_NODES * D * 2);     // 25.6 MB
    ushort* Cqkv   = (ushort*)take((size_t)N_NODES * 384 * 2);   // 76.8 MB
    size_t used = (size_t)(p - (char*)d_ws);
    size_t avail = (ws_size > used) ? ws_size - used : 0;
    int NC = 1;
    if (avail < (size_t)N_NODES * 1152 * 2) NC = 4;
    if (NC == 4 && avail < ((size_t)(N_NODES / 4 + 1) * 1152 * 2)) NC = 8;
    ushort* Ab = (ushort*)p;
    const int chunk = (N_NODES + NC - 1) / NC;

    // dead-buffer alias: Cqkv dead after attention; holds gn2hf (25.6 MB)
    ushort* gn2hf  = Cqkv;

    const int EB = (N_EDGES + 255) / 256;
    const int KB = (NK9 + 8191) / 8192;               // 110 blocks <= scan2's 128
    const int WB = (N_NODES * 64 + 255) / 256;
    const int GB = (N_NODES + 127) / 128;
    const int RB = (N_NODES + 127) / 128;

    // ---- sort edges by (dst, etype)
    hipMemsetAsync(cnt9, 0, (size_t)NK9 * 8, stream);  // cnt9 + cur9
    hist9_kernel<<<EB, 256, 0, stream>>>(dst, ety, cnt9);
    scan1_8<<<KB, 1024, 0, stream>>>(cnt9, rstart, bsum, NK9);
    scan2_kernel<<<1, 128, 0, stream>>>(bsum, KB);
    scan3_8<<<KB, 1024, 0, stream>>>(rstart, bsum, NK9, N_EDGES);
    scatter9_kernel<<<EB, 256, 0, stream>>>(src, dst, ety, rstart, cur9, ssrc, setp);

    // ---- weights (2 dispatches total)
    build_bt_qkv3<<<dim3(640, 3), 256, 0, stream>>>(
        coeffs[0], coeffs[1], coeffs[2], bases[0], bases[1], bases[2],
        loops[0], loops[1], loops[2], pbias[0], pbias[1], pbias[2], Btqkv, biasq);
    transpose_cast3<<<320, 256, 0, stream>>>(o_w, Bto, ffn1_w, Btf1, ffn2_w, Btf2);

    // ---- graph norm 1 -> hnhf (fp16)
    hipMemsetAsync(gsum, 0, (size_t)NG * D * 8, stream);
    gn_stats<<<GB, 256, 0, stream>>>(h, seg, gsum, gsumsq);
    gn_final<<<NG, 128, 0, stream>>>(gsum, gsumsq, seg, gn1_w, gn1_b, gn1_ms, gsc, goff);
    gn_apply<<<WB, 256, 0, stream>>>(h, seg, gsc, goff, hnhf);

    // ---- QKV: S-pass + full-width (384-col) MFMA GEMM per chunk -> Cqkv (fp16)
    for (int c = 0; c < NC; ++c) {
        int c0 = c * chunk;
        int c1 = min(N_NODES, c0 + chunk);
        int rows = c1 - c0;
        if (rows <= 0) break;
        s_pass<<<(rows + 3) / 4, 256, 0, stream>>>(hnhf, ssrc, setp, rstart, Ab, c0, c1);
        mfma_gemm384<<<(rows + 127) / 128, 512, 0, stream>>>(
            hnhf + (size_t)c0 * 128, Ab, rows, Btqkv, biasq, Cqkv + (size_t)c0 * 384);
    }

    // ---- attention -> attnhf (fp16); Cqkv dead after this
    attn_kernel<<<WB, 256, 0, stream>>>(Cqkv, ssrc, rstart, attnhf);

    // ---- output projection + fused ln1 -> h1hf (fp16)
    mfma_gemm_ln<true><<<dim3(1, RB), 256, 0, stream>>>(
        attnhf, 128, N_NODES, Bto, 128, o_b, ln1_g, ln1_b, h1hf);

    // ---- graph norm 2 (fp16 path) -> gn2hf
    hipMemsetAsync(gsum, 0, (size_t)NG * D * 8, stream);
    gn_stats_h<<<GB, 256, 0, stream>>>(h1hf, seg, gsum, gsumsq);
    gn_final<<<NG, 128, 0, stream>>>(gsum, gsumsq, seg, gn2_w, gn2_b, gn2_ms, gsc, goff);
    gn_apply_h<<<WB, 256, 0, stream>>>(h1hf, seg, gsc, goff, gn2hf);

    // ---- fused FFN: relu(gn2hf x W1 + b1) x W2 + b2, + ln2 -> d_out (fp32)
    const int FFN_LDS = (128 * 64 + 256 * 64 + 128 * 256) * 2 + 4 * 128 * 4 * 2;  // 118784
    hipFuncSetAttribute((const void*)ffn_fused, hipFuncAttributeMaxDynamicSharedMemorySize, FFN_LDS);
    ffn_fused<<<RB, 512, FFN_LDS, stream>>>(
        gn2hf, N_NODES, Btf1, ffn1_b, Btf2, ffn2_b, ln2_g, ln2_b, (float*)d_out);
}

// Round 11
// 718.419 us; speedup vs baseline: 1.0451x; 1.0451x over previous
//
#include <hip/hip_runtime.h>
#include <math.h>

#define N_NODES 100000
#define N_EDGES 600000
#define D 128
#define REL 9
#define NG 64
#define NK9 (N_NODES * REL)
#define C1LD 264  // 256 + 8 pad (ushorts): row stride 528 B -> bank stride 4 -> 2-way (free)

typedef float f32x4 __attribute__((ext_vector_type(4)));
typedef _Float16 f16x8 __attribute__((ext_vector_type(8)));
typedef _Float16 h16x2 __attribute__((ext_vector_type(2)));

__device__ __forceinline__ ushort f2h(float x) {
    union { _Float16 h; ushort u; } c; c.h = (_Float16)x; return c.u;
}
__device__ __forceinline__ float h2f(ushort u) {
    union { ushort u; _Float16 h; } c; c.u = u; return (float)c.h;
}

// async global->LDS, 16 B per lane; dest = lds base (wave-uniform) + lane*16
__device__ __forceinline__ void ld16(const ushort* g, ushort* l) {
    __builtin_amdgcn_global_load_lds(
        (const __attribute__((address_space(1))) unsigned int*)g,
        (__attribute__((address_space(3))) unsigned int*)l, 16, 0, 0);
}

__device__ __forceinline__ int lbound(const int* __restrict__ a, int n, int key) {
    int lo = 0, hi = n;
    while (lo < hi) { int mid = (lo + hi) >> 1; if (a[mid] < key) lo = mid + 1; else hi = mid; }
    return lo;
}

// ------------------------------------------------------------ edge sorting by (dst, etype)
__global__ void hist9_kernel(const int* __restrict__ dst, const int* __restrict__ ety,
                             int* __restrict__ cnt9) {
    int e = blockIdx.x * 256 + threadIdx.x;
    if (e < N_EDGES) atomicAdd(&cnt9[dst[e] * REL + ety[e]], 1);
}

// 8 elements per thread -> 8192 per block; NK9=900000 -> 110 blocks (fits scan2's 128)
__global__ void scan1_8(const int* __restrict__ cnt, int* __restrict__ excl,
                        int* __restrict__ bsum, int n) {
    __shared__ int s[1024];
    int tid = threadIdx.x;
    int base = blockIdx.x * 8192 + tid * 8;
    int v[8]; int sum = 0;
#pragma unroll
    for (int j = 0; j < 8; ++j) { v[j] = (base + j < n) ? cnt[base + j] : 0; sum += v[j]; }
    s[tid] = sum;
    __syncthreads();
    for (int off = 1; off < 1024; off <<= 1) {
        int t = (tid >= off) ? s[tid - off] : 0;
        __syncthreads();
        s[tid] += t;
        __syncthreads();
    }
    int run = s[tid] - sum;
#pragma unroll
    for (int j = 0; j < 8; ++j) { if (base + j < n) excl[base + j] = run; run += v[j]; }
    if (tid == 1023) bsum[blockIdx.x] = s[1023];
}

__global__ void scan2_kernel(int* __restrict__ bsum, int nb) {
    __shared__ int s[128];
    int tid = threadIdx.x;
    int v = (tid < nb) ? bsum[tid] : 0;
    s[tid] = v;
    __syncthreads();
    for (int off = 1; off < 128; off <<= 1) {
        int t = (tid >= off) ? s[tid - off] : 0;
        __syncthreads();
        s[tid] += t;
        __syncthreads();
    }
    if (tid < nb) bsum[tid] = s[tid] - v;
}

__global__ void scan3_8(int* __restrict__ excl, const int* __restrict__ bsum, int n, int total) {
    int base = blockIdx.x * 8192 + threadIdx.x * 8;
    int add = bsum[blockIdx.x];
#pragma unroll
    for (int j = 0; j < 8; ++j) if (base + j < n) excl[base + j] += add;
    if (blockIdx.x == 0 && threadIdx.x == 0) excl[n] = total;  // sentinel
}

__global__ void scatter9_kernel(const int* __restrict__ src, const int* __restrict__ dst,
                                const int* __restrict__ ety, const int* __restrict__ rstart,
                                int* __restrict__ cur9, int* __restrict__ ssrc,
                                int* __restrict__ setp) {
    int e = blockIdx.x * 256 + threadIdx.x;
    if (e < N_EDGES) {
        int t = ety[e];
        int key = dst[e] * REL + t;
        int pos = rstart[key] + atomicAdd(&cur9[key], 1);
        ssrc[pos] = src[e];
        setp[pos] = t;
    }
}

// ------------------------------------------------------------- graph norm (moment form)
// Round 8 form (proven): float4 loads + 8 row-phases + per-block LDS reduction,
// ONE atomic pair per (group, channel, block).
__global__ __launch_bounds__(256)
void gn_stats(const float* __restrict__ x, const int* __restrict__ seg,
              float* __restrict__ gsum, float* __restrict__ gsumsq) {
    __shared__ float redS[8][128];
    __shared__ float redQ[8][128];
    int t = threadIdx.x;
    int c4 = (t & 31) * 4;           // 32 threads span 128 channels (float4 each)
    int rr = t >> 5;                 // 8 row-phases in flight
    int n0 = blockIdx.x * 128;
    int nend = min(n0 + 128, N_NODES);
    int len = nend - n0;
    int gfirst = seg[n0];
    int glast = seg[nend - 1];
    for (int g = gfirst; g <= glast; ++g) {
        int lo = (g == gfirst) ? n0 : n0 + lbound(seg + n0, len, g);
        int hi = (g == glast) ? nend : n0 + lbound(seg + n0, len, g + 1);
        float s0 = 0.f, s1 = 0.f, s2 = 0.f, s3 = 0.f;
        float q0 = 0.f, q1 = 0.f, q2 = 0.f, q3 = 0.f;
        for (int n = lo + rr; n < hi; n += 8) {
            float4 v = *(const float4*)&x[(size_t)n * D + c4];
            s0 += v.x; q0 += v.x * v.x;
            s1 += v.y; q1 += v.y * v.y;
            s2 += v.z; q2 += v.z * v.z;
            s3 += v.w; q3 += v.w * v.w;
        }
        redS[rr][c4 + 0] = s0; redS[rr][c4 + 1] = s1;
        redS[rr][c4 + 2] = s2; redS[rr][c4 + 3] = s3;
        redQ[rr][c4 + 0] = q0; redQ[rr][c4 + 1] = q1;
        redQ[rr][c4 + 2] = q2; redQ[rr][c4 + 3] = q3;
        __syncthreads();
        if (t < 128) {
            float ts = 0.f, tq = 0.f;
#pragma unroll
            for (int ph = 0; ph < 8; ++ph) { ts += redS[ph][t]; tq += redQ[ph][t]; }
            atomicAdd(&gsum[g * D + t], ts);
            atomicAdd(&gsumsq[g * D + t], tq);
        }
        __syncthreads();
    }
}

__global__ __launch_bounds__(256)
void gn_stats_h(const ushort* __restrict__ x, const int* __restrict__ seg,
                float* __restrict__ gsum, float* __restrict__ gsumsq) {
    __shared__ float redS[8][128];
    __shared__ float redQ[8][128];
    int t = threadIdx.x;
    int c4 = (t & 31) * 4;
    int rr = t >> 5;
    int n0 = blockIdx.x * 128;
    int nend = min(n0 + 128, N_NODES);
    int len = nend - n0;
    int gfirst = seg[n0];
    int glast = seg[nend - 1];
    for (int g = gfirst; g <= glast; ++g) {
        int lo = (g == gfirst) ? n0 : n0 + lbound(seg + n0, len, g);
        int hi = (g == glast) ? nend : n0 + lbound(seg + n0, len, g + 1);
        float s0 = 0.f, s1 = 0.f, s2 = 0.f, s3 = 0.f;
        float q0 = 0.f, q1 = 0.f, q2 = 0.f, q3 = 0.f;
        for (int n = lo + rr; n < hi; n += 8) {
            ushort4 u = *(const ushort4*)&x[(size_t)n * D + c4];
            float v0 = h2f(u.x), v1 = h2f(u.y), v2 = h2f(u.z), v3 = h2f(u.w);
            s0 += v0; q0 += v0 * v0;
            s1 += v1; q1 += v1 * v1;
            s2 += v2; q2 += v2 * v2;
            s3 += v3; q3 += v3 * v3;
        }
        redS[rr][c4 + 0] = s0; redS[rr][c4 + 1] = s1;
        redS[rr][c4 + 2] = s2; redS[rr][c4 + 3] = s3;
        redQ[rr][c4 + 0] = q0; redQ[rr][c4 + 1] = q1;
        redQ[rr][c4 + 2] = q2; redQ[rr][c4 + 3] = q3;
        __syncthreads();
        if (t < 128) {
            float ts = 0.f, tq = 0.f;
#pragma unroll
            for (int ph = 0; ph < 8; ++ph) { ts += redS[ph][t]; tq += redQ[ph][t]; }
            atomicAdd(&gsum[g * D + t], ts);
            atomicAdd(&gsumsq[g * D + t], tq);
        }
        __syncthreads();
    }
}

__global__ void gn_final(const float* __restrict__ gsum, const float* __restrict__ gsumsq,
                         const int* __restrict__ seg, const float* __restrict__ w,
                         const float* __restrict__ b, const float* __restrict__ ms,
                         float* __restrict__ sc, float* __restrict__ off) {
    int g = blockIdx.x, ch = threadIdx.x;
    int lo = lbound(seg, N_NODES, g), hi = lbound(seg, N_NODES, g + 1);
    float cnt = (float)max(hi - lo, 1);
    float mean = gsum[g * D + ch] / cnt;
    float mm = mean * ms[ch];
    float var = gsumsq[g * D + ch] / cnt - 2.f * mm * mean + mm * mm;
    float rstd = rsqrtf(var + 1e-6f);
    float s = w[ch] * rstd;
    sc[g * D + ch] = s;
    off[g * D + ch] = b[ch] - s * mm;
}

__global__ __launch_bounds__(256)
void gn_apply(const float* __restrict__ x, const int* __restrict__ seg,
              const float* __restrict__ sc, const float* __restrict__ off,
              ushort* __restrict__ outhf) {
    int t = blockIdx.x * 256 + threadIdx.x;
    int n = t >> 6;
    if (n >= N_NODES) return;
    int ch = (t & 63) * 2;
    int g = seg[n];
    float2 xv = *(const float2*)&x[(size_t)n * D + ch];
    float2 s2 = *(const float2*)&sc[g * D + ch];
    float2 o2 = *(const float2*)&off[g * D + ch];
    ushort2 o;
    o.x = f2h(s2.x * xv.x + o2.x);
    o.y = f2h(s2.y * xv.y + o2.y);
    *(ushort2*)&outhf[(size_t)n * D + ch] = o;
}

__global__ __launch_bounds__(256)
void gn_apply_h(const ushort* __restrict__ x, const int* __restrict__ seg,
                const float* __restrict__ sc, const float* __restrict__ off,
                ushort* __restrict__ outhf) {
    int t = blockIdx.x * 256 + threadIdx.x;
    int n = t >> 6;
    if (n >= N_NODES) return;
    int ch = (t & 63) * 2;
    int g = seg[n];
    ushort2 xv = *(const ushort2*)&x[(size_t)n * D + ch];
    float2 s2 = *(const float2*)&sc[g * D + ch];
    float2 o2 = *(const float2*)&off[g * D + ch];
    ushort2 o;
    o.x = f2h(s2.x * h2f(xv.x) + o2.x);
    o.y = f2h(s2.y * h2f(xv.y) + o2.y);
    *(ushort2*)&outhf[(size_t)n * D + ch] = o;
}

// ------------------------- combined QKV weight build (fp16, transposed), all 3 projections
__global__ void build_bt_qkv3(const float* __restrict__ c0, const float* __restrict__ c1,
                              const float* __restrict__ c2, const float* __restrict__ b0,
                              const float* __restrict__ b1, const float* __restrict__ b2,
                              const float* __restrict__ l0, const float* __restrict__ l1,
                              const float* __restrict__ l2, const float* __restrict__ i0,
                              const float* __restrict__ i1, const float* __restrict__ i2,
                              ushort* __restrict__ Btqkv, float* __restrict__ biasq) {
    int pj = blockIdx.y;
    const float* coeff  = pj == 0 ? c0 : (pj == 1 ? c1 : c2);
    const float* basis  = pj == 0 ? b0 : (pj == 1 ? b1 : b2);
    const float* loop_w = pj == 0 ? l0 : (pj == 1 ? l1 : l2);
    const float* bin    = pj == 0 ? i0 : (pj == 1 ? i1 : i2);
    ushort* Bt = Btqkv + (size_t)pj * 128 * 1280;
    int t = blockIdx.x * 256 + threadIdx.x;
    if (t < 128) biasq[pj * 128 + t] = bin[t];
    if (t >= 128 * 1280) return;
    int o = t / 1280;
    int k = t - o * 1280;
    float v;
    if (k < 128) {
        v = loop_w[k * 128 + o];
    } else {
        int kk = k - 128;
        int r = kk >> 7, i = kk & 127;
        v = 0.f;
#pragma unroll
        for (int b = 0; b < REL; ++b)
            v += coeff[r * REL + b] * basis[((size_t)b * 128 + i) * 128 + o];
    }
    Bt[(size_t)o * 1280 + k] = f2h(v);
}

// single launch for o_w / ffn1 / ffn2 transposed fp16 weights
__global__ void transpose_cast3(const float* __restrict__ o_w, ushort* __restrict__ Bto,
                                const float* __restrict__ f1, ushort* __restrict__ Btf1,
                                const float* __restrict__ f2, ushort* __restrict__ Btf2) {
    int t = blockIdx.x * 256 + threadIdx.x;
    if (t < 16384) {                 // o_w: I=128, O=128
        int n = t >> 7, k = t & 127;
        Bto[(size_t)n * 128 + k] = f2h(o_w[(size_t)k * 128 + n]);
    } else if (t < 49152) {          // ffn1: I=128, O=256
        int u = t - 16384;
        int n = u >> 7, k = u & 127;
        Btf1[(size_t)n * 128 + k] = f2h(f1[(size_t)k * 256 + n]);
    } else if (t < 81920) {          // ffn2: I=256, O=128
        int u = t - 49152;
        int n = u >> 8, k = u & 255;
        Btf2[(size_t)n * 256 + k] = f2h(f2[(size_t)k * 128 + n]);
    }
}

// ----------------------------------------- per-relation gathered sums -> Ab rows (fp16, 1152)
// half2 packed accumulation; 4-edge unroll (proven r9).
__global__ __launch_bounds__(256)
void s_pass(const ushort* __restrict__ hnhf, const int* __restrict__ ssrc,
            const int* __restrict__ setp, const int* __restrict__ rstart,
            ushort* __restrict__ Ab, int c0, int c1) {
    int n = c0 + ((blockIdx.x * 256 + threadIdx.x) >> 6);
    if (n >= c1) return;
    int lane = threadIdx.x & 63;
    int e0 = rstart[n * REL], e1 = rstart[n * REL + REL];
    h16x2 a0 = (h16x2)0, a1 = (h16x2)0, a2 = (h16x2)0, a3 = (h16x2)0, a4 = (h16x2)0;
    h16x2 a5 = (h16x2)0, a6 = (h16x2)0, a7 = (h16x2)0, a8 = (h16x2)0;
#define ACC(rr, hv) switch (rr) { \
        case 0: a0 += hv; break; case 1: a1 += hv; break; case 2: a2 += hv; break; \
        case 3: a3 += hv; break; case 4: a4 += hv; break; case 5: a5 += hv; break; \
        case 6: a6 += hv; break; case 7: a7 += hv; break; default: a8 += hv; break; }
    int e = e0;
    for (; e + 4 <= e1; e += 4) {
        int s0 = ssrc[e], s1 = ssrc[e + 1], s2 = ssrc[e + 2], s3 = ssrc[e + 3];
        int r0 = __builtin_amdgcn_readfirstlane(setp[e]);
        int r1 = __builtin_amdgcn_readfirstlane(setp[e + 1]);
        int r2 = __builtin_amdgcn_readfirstlane(setp[e + 2]);
        int r3 = __builtin_amdgcn_readfirstlane(setp[e + 3]);
        h16x2 hv0 = *(const h16x2*)&hnhf[(size_t)s0 * D + 2 * lane];
        h16x2 hv1 = *(const h16x2*)&hnhf[(size_t)s1 * D + 2 * lane];
        h16x2 hv2 = *(const h16x2*)&hnhf[(size_t)s2 * D + 2 * lane];
        h16x2 hv3 = *(const h16x2*)&hnhf[(size_t)s3 * D + 2 * lane];
        ACC(r0, hv0)
        ACC(r1, hv1)
        ACC(r2, hv2)
        ACC(r3, hv3)
    }
    for (; e < e1; ++e) {
        int s0 = ssrc[e];
        int r0 = __builtin_amdgcn_readfirstlane(setp[e]);
        h16x2 hv0 = *(const h16x2*)&hnhf[(size_t)s0 * D + 2 * lane];
        ACC(r0, hv0)
    }
#undef ACC
    ushort* arow = Ab + (size_t)(n - c0) * 1152;
#define ST(r) *(h16x2*)&arow[r * 128 + 2 * lane] = a##r;
    ST(0) ST(1) ST(2) ST(3) ST(4) ST(5) ST(6) ST(7) ST(8)
#undef ST
}

// ---------------------------------------------------- QKV MFMA GEMM, full 384-col block
// Block = 128 rows x ALL 384 cols (A read ONCE).
// 512 threads, 8 waves (2 row-halves x 4 col-quarters), acc[4][6]; LDS 64 KB (2 blk/CU).
// K: 0..127 from hnhf (lda 128), 128..1279 from Ab (lda 1152, col k-128).
__global__ __launch_bounds__(512)
void mfma_gemm384(const ushort* __restrict__ A1, const ushort* __restrict__ Ab, int M,
                  const ushort* __restrict__ Bt, const float* __restrict__ bias,
                  ushort* __restrict__ Cout) {
    __shared__ ushort As[128 * 64];
    __shared__ ushort Bs[384 * 64];
    const int tid = threadIdx.x;
    const int lane = tid & 63;
    const int wave = tid >> 6;               // 0..7
    const int wm = wave & 1, wn = wave >> 1; // 2 row-halves x 4 col-quarters
    const int quad = lane >> 4, l16 = lane & 15;
    const int row0 = blockIdx.x * 128;

    const ushort* sA1[2];
    const ushort* sA2[2];
#pragma unroll
    for (int i = 0; i < 2; ++i) {
        int rs = (wave * 2 + i) * 8 + (lane >> 3);
        int kg = (lane & 7) ^ (rs & 7);
        int ra = row0 + rs; if (ra >= M) ra = M - 1;
        sA1[i] = A1 + (size_t)ra * 128 + kg * 8;
        sA2[i] = Ab + (size_t)ra * 1152 + kg * 8;
    }
    const ushort* sB[6];
#pragma unroll
    for (int i = 0; i < 6; ++i) {
        int rs = (wave * 6 + i) * 8 + (lane >> 3);
        int kg = (lane & 7) ^ (rs & 7);
        sB[i] = Bt + (size_t)rs * 1280 + kg * 8;
    }

    f32x4 acc[4][6];
#pragma unroll
    for (int i = 0; i < 4; ++i)
#pragma unroll
        for (int j = 0; j < 6; ++j) acc[i][j] = (f32x4){0.f, 0.f, 0.f, 0.f};

    for (int kc = 0; kc < 1280; kc += 64) {
#pragma unroll
        for (int i = 0; i < 6; ++i) ld16(sB[i] + kc, &Bs[(wave * 6 + i) * 512]);
#pragma unroll
        for (int i = 0; i < 2; ++i) {
            const ushort* as = (kc < 128) ? (sA1[i] + kc) : (sA2[i] + (kc - 128));
            ld16(as, &As[(wave * 2 + i) * 512]);
        }
        __syncthreads();
#pragma unroll
        for (int h = 0; h < 2; ++h) {
            f16x8 af[4], bf[6];
#pragma unroll
            for (int i = 0; i < 4; ++i) {
                int r = wm * 64 + i * 16 + l16;
                af[i] = *(const f16x8*)&As[r * 64 + (((h * 4 + quad) ^ (r & 7)) * 8)];
            }
#pragma unroll
            for (int j = 0; j < 6; ++j) {
                int c = wn * 96 + j * 16 + l16;
                bf[j] = *(const f16x8*)&Bs[c * 64 + (((h * 4 + quad) ^ (c & 7)) * 8)];
            }
#pragma unroll
            for (int i = 0; i < 4; ++i)
#pragma unroll
                for (int j = 0; j < 6; ++j)
                    acc[i][j] = __builtin_amdgcn_mfma_f32_16x16x32_f16(af[i], bf[j], acc[i][j], 0, 0, 0);
        }
        __syncthreads();
    }

#pragma unroll
    for (int i = 0; i < 4; ++i) {
        int gr0 = wm * 64 + i * 16 + quad * 4 + row0;
#pragma unroll
        for (int r = 0; r < 4; ++r) {
            int gr = gr0 + r;
            if (gr >= M) continue;
#pragma unroll
            for (int j = 0; j < 6; ++j) {
                int gcol = wn * 96 + j * 16 + l16;
                float v = acc[i][j][r] + bias[gcol];
                v = fmaxf(v, 0.f);
                Cout[(size_t)gr * 384 + gcol] = f2h(v);
            }
        }
    }
}

// ------------------------------------------------ fp16 MFMA GEMM + fused row LayerNorm
// (o-projection + ln1; 256 threads, 4 waves)
template<bool F16OUT>
__global__ __launch_bounds__(256, 3)
void mfma_gemm_ln(const ushort* __restrict__ A, int lda, int M,
                  const ushort* __restrict__ Bt, int K,
                  const float* __restrict__ bias, const float* __restrict__ lng,
                  const float* __restrict__ lnb, void* __restrict__ Cout) {
    __shared__ ushort As[128 * 64];
    __shared__ ushort Bs[128 * 64];
    __shared__ float rsum[2][128];
    __shared__ float rsq[2][128];
    const int tid = threadIdx.x;
    const int lane = tid & 63;
    const int wave = tid >> 6;
    const int wm = wave & 1, wn = wave >> 1;
    const int quad = lane >> 4, l16 = lane & 15;
    const int row0 = blockIdx.y * 128;

    const ushort* sA[4];
    const ushort* sB[4];
#pragma unroll
    for (int i = 0; i < 4; ++i) {
        int rs = (wave * 4 + i) * 8 + (lane >> 3);
        int kg = (lane & 7) ^ (rs & 7);
        int ra = row0 + rs; if (ra >= M) ra = M - 1;
        sA[i] = A + (size_t)ra * lda + kg * 8;
        sB[i] = Bt + (size_t)rs * K + kg * 8;
    }

    f32x4 acc[4][4];
#pragma unroll
    for (int i = 0; i < 4; ++i)
#pragma unroll
        for (int j = 0; j < 4; ++j) acc[i][j] = (f32x4){0.f, 0.f, 0.f, 0.f};

    for (int kc = 0; kc < K; kc += 64) {
#pragma unroll
        for (int i = 0; i < 4; ++i) {
            ld16(sA[i] + kc, &As[(wave * 4 + i) * 512]);
            ld16(sB[i] + kc, &Bs[(wave * 4 + i) * 512]);
        }
        __syncthreads();
#pragma unroll
        for (int h = 0; h < 2; ++h) {
            f16x8 af[4], bf[4];
#pragma unroll
            for (int i = 0; i < 4; ++i) {
                int r = wm * 64 + i * 16 + l16;
                af[i] = *(const f16x8*)&As[r * 64 + (((h * 4 + quad) ^ (r & 7)) * 8)];
                int c = wn * 64 + i * 16 + l16;
                bf[i] = *(const f16x8*)&Bs[c * 64 + (((h * 4 + quad) ^ (c & 7)) * 8)];
            }
#pragma unroll
            for (int i = 0; i < 4; ++i)
#pragma unroll
                for (int j = 0; j < 4; ++j)
                    acc[i][j] = __builtin_amdgcn_mfma_f32_16x16x32_f16(af[i], bf[j], acc[i][j], 0, 0, 0);
        }
        __syncthreads();
    }

#pragma unroll
    for (int i = 0; i < 4; ++i) {
#pragma unroll
        for (int r = 0; r < 4; ++r) {
            float s = 0.f, q = 0.f;
#pragma unroll
            for (int j = 0; j < 4; ++j) {
                float v = acc[i][j][r] + bias[wn * 64 + j * 16 + l16];
                s += v; q += v * v;
            }
            s += __shfl_xor(s, 1); q += __shfl_xor(q, 1);
            s += __shfl_xor(s, 2); q += __shfl_xor(q, 2);
            s += __shfl_xor(s, 4); q += __shfl_xor(q, 4);
            s += __shfl_xor(s, 8); q += __shfl_xor(q, 8);
            if (l16 == 0) {
                int row = wm * 64 + i * 16 + quad * 4 + r;
                rsum[wn][row] = s;
                rsq[wn][row] = q;
            }
        }
    }
    __syncthreads();

#pragma unroll
    for (int i = 0; i < 4; ++i) {
#pragma unroll
        for (int r = 0; r < 4; ++r) {
            int row = wm * 64 + i * 16 + quad * 4 + r;
            int grow = row0 + row;
            if (grow >= M) continue;
            float tot = rsum[0][row] + rsum[1][row];
            float tq  = rsq[0][row] + rsq[1][row];
            float mu = tot * (1.f / 128.f);
            float var = tq * (1.f / 128.f) - mu * mu;
            float rstd = rsqrtf(var + 1e-5f);
#pragma unroll
            for (int j = 0; j < 4; ++j) {
                int gcol = wn * 64 + j * 16 + l16;
                float v = acc[i][j][r] + bias[gcol];
                float o = lng[gcol] * (v - mu) * rstd + lnb[gcol];
                if (F16OUT) ((ushort*)Cout)[(size_t)grow * 128 + gcol] = f2h(o);
                else        ((float*)Cout)[(size_t)grow * 128 + gcol] = o;
            }
        }
    }
}

// ---------------------------------------------------------------- fused FFN v2 (round 11)
// 64-row blocks: LDS 75 KB -> 2 blocks/CU (round-10's 116 KB/1-blk was the occupancy
// binder: 16% occ, MfmaUtil 7%). C1 kept in plain row-major with +8-ushort pad
// (stride 264: row stride 528 B -> bank stride 4 -> 2-way aliasing = free), replacing
// the XOR-swizzled scalar stores that caused 800K bank conflicts.
__global__ __launch_bounds__(512)
void ffn_fused(const ushort* __restrict__ A, int M,
               const ushort* __restrict__ B1t, const float* __restrict__ b1,
               const ushort* __restrict__ B2t, const float* __restrict__ b2,
               const float* __restrict__ lng, const float* __restrict__ lnb,
               float* __restrict__ Cout) {
    extern __shared__ ushort sh[];
    ushort* As   = sh;                           // 64*64   =  8 KB
    ushort* Bs   = sh + 64 * 64;                 // 256*64  = 32 KB (phase1) / 128*64 (phase2)
    ushort* C1s  = sh + 64 * 64 + 256 * 64;      // 64*264  = 33 KB
    float*  rsum = (float*)(C1s + 64 * C1LD);    // [4][64]
    float*  rsq  = rsum + 4 * 64;
    const int tid = threadIdx.x;
    const int lane = tid & 63;
    const int wave = tid >> 6;               // 0..7
    const int wm = wave & 1, wn = wave >> 1; // 2 row-halves(32) x 4 col groups
    const int quad = lane >> 4, l16 = lane & 15;
    const int row0 = blockIdx.x * 64;

    // ---------------- phase 1: C1 = relu(A x B1t + b1), 64x256, K=128
    {
        int rsA = wave * 8 + (lane >> 3);
        int kgA = (lane & 7) ^ (rsA & 7);
        int raA = row0 + rsA; if (raA >= M) raA = M - 1;
        const ushort* sA = A + (size_t)raA * 128 + kgA * 8;
        const ushort* sB[4];
#pragma unroll
        for (int i = 0; i < 4; ++i) {
            int rs = (wave * 4 + i) * 8 + (lane >> 3);
            int kg = (lane & 7) ^ (rs & 7);
            sB[i] = B1t + (size_t)rs * 128 + kg * 8;
        }
        f32x4 acc[2][4];
#pragma unroll
        for (int i = 0; i < 2; ++i)
#pragma unroll
            for (int j = 0; j < 4; ++j) acc[i][j] = (f32x4){0.f, 0.f, 0.f, 0.f};

        for (int kc = 0; kc < 128; kc += 64) {
#pragma unroll
            for (int i = 0; i < 4; ++i) ld16(sB[i] + kc, &Bs[(wave * 4 + i) * 512]);
            ld16(sA + kc, &As[wave * 512]);
            __syncthreads();
#pragma unroll
            for (int h = 0; h < 2; ++h) {
                f16x8 af[2], bf[4];
#pragma unroll
                for (int i = 0; i < 2; ++i) {
                    int r = wm * 32 + i * 16 + l16;
                    af[i] = *(const f16x8*)&As[r * 64 + (((h * 4 + quad) ^ (r & 7)) * 8)];
                }
#pragma unroll
                for (int j = 0; j < 4; ++j) {
                    int c = wn * 64 + j * 16 + l16;
                    bf[j] = *(const f16x8*)&Bs[c * 64 + (((h * 4 + quad) ^ (c & 7)) * 8)];
                }
#pragma unroll
                for (int i = 0; i < 2; ++i)
#pragma unroll
                    for (int j = 0; j < 4; ++j)
                        acc[i][j] = __builtin_amdgcn_mfma_f32_16x16x32_f16(af[i], bf[j], acc[i][j], 0, 0, 0);
            }
            __syncthreads();
        }

        // epilogue: relu + bias -> C1s (row-major, +8 pad); lanes write 16 consecutive
        // ushorts per (i,j,r) -> conflict-free.
#pragma unroll
        for (int i = 0; i < 2; ++i) {
            int lr0 = wm * 32 + i * 16 + quad * 4;
#pragma unroll
            for (int r = 0; r < 4; ++r) {
                int row = lr0 + r;
#pragma unroll
                for (int j = 0; j < 4; ++j) {
                    int col = wn * 64 + j * 16 + l16;
                    float v = acc[i][j][r] + b1[col];
                    v = fmaxf(v, 0.f);
                    C1s[row * C1LD + col] = f2h(v);
                }
            }
        }
    }
    __syncthreads();

    // ---------------- phase 2: C2 = C1 x B2t + b2 (+row-LN), 64x128, K=256
    {
        const ushort* sB[2];
#pragma unroll
        for (int i = 0; i < 2; ++i) {
            int rs = (wave * 2 + i) * 8 + (lane >> 3);
            int kg = (lane & 7) ^ (rs & 7);
            sB[i] = B2t + (size_t)rs * 256 + kg * 8;
        }
        f32x4 acc[2][2];
#pragma unroll
        for (int i = 0; i < 2; ++i)
#pragma unroll
            for (int j = 0; j < 2; ++j) acc[i][j] = (f32x4){0.f, 0.f, 0.f, 0.f};

        for (int kc = 0; kc < 256; kc += 64) {
#pragma unroll
            for (int i = 0; i < 2; ++i) ld16(sB[i] + kc, &Bs[(wave * 2 + i) * 512]);
            __syncthreads();
#pragma unroll
            for (int h = 0; h < 2; ++h) {
                f16x8 af[2], bf[2];
#pragma unroll
                for (int i = 0; i < 2; ++i) {
                    int r = wm * 32 + i * 16 + l16;
                    af[i] = *(const f16x8*)&C1s[r * C1LD + kc + ((h * 4 + quad) * 8)];
                }
#pragma unroll
                for (int j = 0; j < 2; ++j) {
                    int c = wn * 32 + j * 16 + l16;
                    bf[j] = *(const f16x8*)&Bs[c * 64 + (((h * 4 + quad) ^ (c & 7)) * 8)];
                }
#pragma unroll
                for (int i = 0; i < 2; ++i)
#pragma unroll
                    for (int j = 0; j < 2; ++j)
                        acc[i][j] = __builtin_amdgcn_mfma_f32_16x16x32_f16(af[i], bf[j], acc[i][j], 0, 0, 0);
            }
            __syncthreads();
        }

        // row-LN across the 4 col groups
#pragma unroll
        for (int i = 0; i < 2; ++i) {
#pragma unroll
            for (int r = 0; r < 4; ++r) {
                float s = 0.f, q = 0.f;
#pragma unroll
                for (int j = 0; j < 2; ++j) {
                    float v = acc[i][j][r] + b2[wn * 32 + j * 16 + l16];
                    s += v; q += v * v;
                }
                s += __shfl_xor(s, 1); q += __shfl_xor(q, 1);
                s += __shfl_xor(s, 2); q += __shfl_xor(q, 2);
                s += __shfl_xor(s, 4); q += __shfl_xor(q, 4);
                s += __shfl_xor(s, 8); q += __shfl_xor(q, 8);
                if (l16 == 0) {
                    int row = wm * 32 + i * 16 + quad * 4 + r;
                    rsum[wn * 64 + row] = s;
                    rsq[wn * 64 + row] = q;
                }
            }
        }
        __syncthreads();

#pragma unroll
        for (int i = 0; i < 2; ++i) {
#pragma unroll
            for (int r = 0; r < 4; ++r) {
                int row = wm * 32 + i * 16 + quad * 4 + r;
                int grow = row0 + row;
                if (grow >= M) continue;
                float tot = rsum[row] + rsum[64 + row] + rsum[128 + row] + rsum[192 + row];
                float tq  = rsq[row] + rsq[64 + row] + rsq[128 + row] + rsq[192 + row];
                float mu = tot * (1.f / 128.f);
                float var = tq * (1.f / 128.f) - mu * mu;
                float rstd = rsqrtf(var + 1e-5f);
#pragma unroll
                for (int j = 0; j < 2; ++j) {
                    int gcol = wn * 32 + j * 16 + l16;
                    float v = acc[i][j][r] + b2[gcol];
                    float o = lng[gcol] * (v - mu) * rstd + lnb[gcol];
                    Cout[(size_t)grow * 128 + gcol] = o;
                }
            }
        }
    }
}

// --------------------------------------------------------------- attention
// 8-edge unroll (proven r9); at gather-BW plateau (~3.5 TB/s) — don't touch.
__global__ __launch_bounds__(256)
void attn_kernel(const ushort* __restrict__ C, const int* __restrict__ ssrc,
                 const int* __restrict__ rstart, ushort* __restrict__ attnhf) {
    int n = (blockIdx.x * 256 + threadIdx.x) >> 6;
    if (n >= N_NODES) return;
    int lane = threadIdx.x & 63;
    h16x2 qh = *(const h16x2*)&C[(size_t)n * 384 + 2 * lane];
    int e0 = rstart[n * REL], e1 = rstart[n * REL + REL];
    float wvx = 0.f, wvy = 0.f, z = 0.f;
    int e = e0;
    for (; e + 8 <= e1; e += 8) {
        int s[8];
#pragma unroll
        for (int j = 0; j < 8; ++j) s[j] = ssrc[e + j];
        h16x2 kk[8], vv[8];
#pragma unroll
        for (int j = 0; j < 8; ++j) kk[j] = *(const h16x2*)&C[(size_t)s[j] * 384 + 128 + 2 * lane];
#pragma unroll
        for (int j = 0; j < 8; ++j) vv[j] = *(const h16x2*)&C[(size_t)s[j] * 384 + 256 + 2 * lane];
        float d[8];
#pragma unroll
        for (int j = 0; j < 8; ++j) d[j] = __builtin_amdgcn_fdot2(kk[j], qh, 0.f, false);
#pragma unroll
        for (int j = 0; j < 8; ++j) d[j] += __shfl_xor(d[j], 1);
#pragma unroll
        for (int j = 0; j < 8; ++j) d[j] += __shfl_xor(d[j], 2);
#pragma unroll
        for (int j = 0; j < 8; ++j) d[j] += __shfl_xor(d[j], 4);
#pragma unroll
        for (int j = 0; j < 8; ++j) {
            float sc = __expf(fminf(fmaxf(d[j] * 0.25f, -10.f), 10.f));
            wvx += sc * (float)vv[j].x;
            wvy += sc * (float)vv[j].y;
            z += sc;
        }
    }
    for (; e + 4 <= e1; e += 4) {
        int s0 = ssrc[e], s1 = ssrc[e + 1], s2 = ssrc[e + 2], s3 = ssrc[e + 3];
        h16x2 k0 = *(const h16x2*)&C[(size_t)s0 * 384 + 128 + 2 * lane];
        h16x2 k1 = *(const h16x2*)&C[(size_t)s1 * 384 + 128 + 2 * lane];
        h16x2 k2 = *(const h16x2*)&C[(size_t)s2 * 384 + 128 + 2 * lane];
        h16x2 k3 = *(const h16x2*)&C[(size_t)s3 * 384 + 128 + 2 * lane];
        h16x2 v0 = *(const h16x2*)&C[(size_t)s0 * 384 + 256 + 2 * lane];
        h16x2 v1 = *(const h16x2*)&C[(size_t)s1 * 384 + 256 + 2 * lane];
        h16x2 v2 = *(const h16x2*)&C[(size_t)s2 * 384 + 256 + 2 * lane];
        h16x2 v3 = *(const h16x2*)&C[(size_t)s3 * 384 + 256 + 2 * lane];
        float d0 = __builtin_amdgcn_fdot2(k0, qh, 0.f, false);
        float d1 = __builtin_amdgcn_fdot2(k1, qh, 0.f, false);
        float d2 = __builtin_amdgcn_fdot2(k2, qh, 0.f, false);
        float d3 = __builtin_amdgcn_fdot2(k3, qh, 0.f, false);
        d0 += __shfl_xor(d0, 1); d1 += __shfl_xor(d1, 1);
        d2 += __shfl_xor(d2, 1); d3 += __shfl_xor(d3, 1);
        d0 += __shfl_xor(d0, 2); d1 += __shfl_xor(d1, 2);
        d2 += __shfl_xor(d2, 2); d3 += __shfl_xor(d3, 2);
        d0 += __shfl_xor(d0, 4); d1 += __shfl_xor(d1, 4);
        d2 += __shfl_xor(d2, 4); d3 += __shfl_xor(d3, 4);
        float sc0 = __expf(fminf(fmaxf(d0 * 0.25f, -10.f), 10.f));
        float sc1 = __expf(fminf(fmaxf(d1 * 0.25f, -10.f), 10.f));
        float sc2 = __expf(fminf(fmaxf(d2 * 0.25f, -10.f), 10.f));
        float sc3 = __expf(fminf(fmaxf(d3 * 0.25f, -10.f), 10.f));
        wvx += sc0 * (float)v0.x + sc1 * (float)v1.x;
        wvy += sc0 * (float)v0.y + sc1 * (float)v1.y;
        wvx += sc2 * (float)v2.x + sc3 * (float)v3.x;
        wvy += sc2 * (float)v2.y + sc3 * (float)v3.y;
        z += sc0 + sc1 + sc2 + sc3;
    }
    for (; e < e1; ++e) {
        int s0 = ssrc[e];
        h16x2 k0 = *(const h16x2*)&C[(size_t)s0 * 384 + 128 + 2 * lane];
        h16x2 v0 = *(const h16x2*)&C[(size_t)s0 * 384 + 256 + 2 * lane];
        float d0 = __builtin_amdgcn_fdot2(k0, qh, 0.f, false);
        d0 += __shfl_xor(d0, 1);
        d0 += __shfl_xor(d0, 2);
        d0 += __shfl_xor(d0, 4);
        float sc0 = __expf(fminf(fmaxf(d0 * 0.25f, -10.f), 10.f));
        wvx += sc0 * (float)v0.x;
        wvy += sc0 * (float)v0.y;
        z += sc0;
    }
    float inv = 1.f / (z + 1e-6f);
    ushort2 o;
    o.x = f2h(wvx * inv);
    o.y = f2h(wvy * inv);
    *(ushort2*)&attnhf[(size_t)n * D + 2 * lane] = o;
}

// ------------------------------------------------------------------ launch
extern "C" void kernel_launch(void* const* d_in, const int* in_sizes, int n_in,
                              void* d_out, int out_size, void* d_ws, size_t ws_size,
                              hipStream_t stream) {
    (void)in_sizes; (void)n_in; (void)out_size;
    const float* h     = (const float*)d_in[0];
    const int*   src   = (const int*)d_in[1];
    const int*   dst   = (const int*)d_in[2];
    const int*   ety   = (const int*)d_in[3];
    const int*   seg   = (const int*)d_in[4];
    const float* coeffs[3] = {(const float*)d_in[6],  (const float*)d_in[10], (const float*)d_in[14]};
    const float* bases [3] = {(const float*)d_in[7],  (const float*)d_in[11], (const float*)d_in[15]};
    const float* loops [3] = {(const float*)d_in[8],  (const float*)d_in[12], (const float*)d_in[16]};
    const float* pbias [3] = {(const float*)d_in[9],  (const float*)d_in[13], (const float*)d_in[17]};
    const float* o_w   = (const float*)d_in[18];
    const float* o_b   = (const float*)d_in[19];
    const float* gn1_w = (const float*)d_in[20];
    const float* gn1_b = (const float*)d_in[21];
    const float* gn1_ms= (const float*)d_in[22];
    const float* gn2_w = (const float*)d_in[23];
    const float* gn2_b = (const float*)d_in[24];
    const float* gn2_ms= (const float*)d_in[25];
    const float* ln1_g = (const float*)d_in[26];
    const float* ln1_b = (const float*)d_in[27];
    const float* ln2_g = (const float*)d_in[28];
    const float* ln2_b = (const float*)d_in[29];
    const float* ffn1_w= (const float*)d_in[30];
    const float* ffn1_b= (const float*)d_in[31];
    const float* ffn2_w= (const float*)d_in[32];
    const float* ffn2_b= (const float*)d_in[33];

    char* p = (char*)d_ws;
    auto take = [&](size_t bytes) { char* r = p; p += (bytes + 255) & ~(size_t)255; return r; };
    int*    cnt9   = (int*)take((size_t)NK9 * 2 * 4);   // cnt9 + cur9, single memset
    int*    cur9   = cnt9 + NK9;
    int*    rstart = (int*)take((size_t)(NK9 + 8) * 4); // +sentinel
    int*    bsum   = (int*)take(512);
    int*    ssrc   = (int*)take((size_t)N_EDGES * 4);
    int*    setp   = (int*)take((size_t)N_EDGES * 4);
    float*  gsum   = (float*)take((size_t)NG * D * 4 * 2);
    float*  gsumsq = gsum + NG * D;
    float*  gsc    = (float*)take((size_t)NG * D * 4);
    float*  goff   = (float*)take((size_t)NG * D * 4);
    ushort* Btqkv  = (ushort*)take((size_t)384 * 1280 * 2);
    float*  biasq  = (float*)take(384 * 4);
    ushort* Bto    = (ushort*)take((size_t)128 * 128 * 2);
    ushort* Btf1   = (ushort*)take((size_t)256 * 128 * 2);
    ushort* Btf2   = (ushort*)take((size_t)128 * 256 * 2);
    ushort* hnhf   = (ushort*)take((size_t)N_NODES * D * 2);     // 25.6 MB
    ushort* attnhf = (ushort*)take((size_t)N_NODES * D * 2);     // 25.6 MB
    ushort* h1hf   = (ushort*)take((size_t)N_NODES * D * 2);     // 25.6 MB
    ushort* Cqkv   = (ushort*)take((size_t)N_NODES * 384 * 2);   // 76.8 MB
    size_t used = (size_t)(p - (char*)d_ws);
    size_t avail = (ws_size > used) ? ws_size - used : 0;
    int NC = 1;
    if (avail < (size_t)N_NODES * 1152 * 2) NC = 4;
    if (NC == 4 && avail < ((size_t)(N_NODES / 4 + 1) * 1152 * 2)) NC = 8;
    ushort* Ab = (ushort*)p;
    const int chunk = (N_NODES + NC - 1) / NC;

    // dead-buffer alias: Cqkv dead after attention; holds gn2hf (25.6 MB)
    ushort* gn2hf  = Cqkv;

    const int EB = (N_EDGES + 255) / 256;
    const int KB = (NK9 + 8191) / 8192;               // 110 blocks <= scan2's 128
    const int WB = (N_NODES * 64 + 255) / 256;
    const int GB = (N_NODES + 127) / 128;
    const int RB = (N_NODES + 127) / 128;
    const int FB = (N_NODES + 63) / 64;

    // ---- sort edges by (dst, etype)
    hipMemsetAsync(cnt9, 0, (size_t)NK9 * 8, stream);  // cnt9 + cur9
    hist9_kernel<<<EB, 256, 0, stream>>>(dst, ety, cnt9);
    scan1_8<<<KB, 1024, 0, stream>>>(cnt9, rstart, bsum, NK9);
    scan2_kernel<<<1, 128, 0, stream>>>(bsum, KB);
    scan3_8<<<KB, 1024, 0, stream>>>(rstart, bsum, NK9, N_EDGES);
    scatter9_kernel<<<EB, 256, 0, stream>>>(src, dst, ety, rstart, cur9, ssrc, setp);

    // ---- weights (2 dispatches total)
    build_bt_qkv3<<<dim3(640, 3), 256, 0, stream>>>(
        coeffs[0], coeffs[1], coeffs[2], bases[0], bases[1], bases[2],
        loops[0], loops[1], loops[2], pbias[0], pbias[1], pbias[2], Btqkv, biasq);
    transpose_cast3<<<320, 256, 0, stream>>>(o_w, Bto, ffn1_w, Btf1, ffn2_w, Btf2);

    // ---- graph norm 1 -> hnhf (fp16)
    hipMemsetAsync(gsum, 0, (size_t)NG * D * 8, stream);
    gn_stats<<<GB, 256, 0, stream>>>(h, seg, gsum, gsumsq);
    gn_final<<<NG, 128, 0, stream>>>(gsum, gsumsq, seg, gn1_w, gn1_b, gn1_ms, gsc, goff);
    gn_apply<<<WB, 256, 0, stream>>>(h, seg, gsc, goff, hnhf);

    // ---- QKV: S-pass + full-width (384-col) MFMA GEMM per chunk -> Cqkv (fp16)
    for (int c = 0; c < NC; ++c) {
        int c0 = c * chunk;
        int c1 = min(N_NODES, c0 + chunk);
        int rows = c1 - c0;
        if (rows <= 0) break;
        s_pass<<<(rows + 3) / 4, 256, 0, stream>>>(hnhf, ssrc, setp, rstart, Ab, c0, c1);
        mfma_gemm384<<<(rows + 127) / 128, 512, 0, stream>>>(
            hnhf + (size_t)c0 * 128, Ab, rows, Btqkv, biasq, Cqkv + (size_t)c0 * 384);
    }

    // ---- attention -> attnhf (fp16); Cqkv dead after this
    attn_kernel<<<WB, 256, 0, stream>>>(Cqkv, ssrc, rstart, attnhf);

    // ---- output projection + fused ln1 -> h1hf (fp16)
    mfma_gemm_ln<true><<<dim3(1, RB), 256, 0, stream>>>(
        attnhf, 128, N_NODES, Bto, 128, o_b, ln1_g, ln1_b, h1hf);

    // ---- graph norm 2 (fp16 path) -> gn2hf
    hipMemsetAsync(gsum, 0, (size_t)NG * D * 8, stream);
    gn_stats_h<<<GB, 256, 0, stream>>>(h1hf, seg, gsum, gsumsq);
    gn_final<<<NG, 128, 0, stream>>>(gsum, gsumsq, seg, gn2_w, gn2_b, gn2_ms, gsc, goff);
    gn_apply_h<<<WB, 256, 0, stream>>>(h1hf, seg, gsc, goff, gn2hf);

    // ---- fused FFN v2: relu(gn2hf x W1 + b1) x W2 + b2, + ln2 -> d_out (fp32)
    const int FFN_LDS = (64 * 64 + 256 * 64 + 64 * C1LD) * 2 + 2 * 4 * 64 * 4;  // 76800
    hipFuncSetAttribute((const void*)ffn_fused, hipFuncAttributeMaxDynamicSharedMemorySize, FFN_LDS);
    ffn_fused<<<FB, 512, FFN_LDS, stream>>>(
        gn2hf, N_NODES, Btf1, ffn1_b, Btf2, ffn2_b, ln2_g, ln2_b, (float*)d_out);
}

// Round 12
// 704.542 us; speedup vs baseline: 1.0657x; 1.0197x over previous
//
#include <hip/hip_runtime.h>
#include <math.h>

#define N_NODES 100000
#define N_EDGES 600000
#define D 128
#define REL 9
#define NG 64
#define NK9 (N_NODES * REL)
#define C1LD 264  // 256 + 8 pad (ushorts): row stride 528 B -> bank stride 4 -> 2-way (free)

typedef float f32x4 __attribute__((ext_vector_type(4)));
typedef _Float16 f16x8 __attribute__((ext_vector_type(8)));
typedef _Float16 h16x2 __attribute__((ext_vector_type(2)));

__device__ __forceinline__ ushort f2h(float x) {
    union { _Float16 h; ushort u; } c; c.h = (_Float16)x; return c.u;
}
__device__ __forceinline__ float h2f(ushort u) {
    union { ushort u; _Float16 h; } c; c.u = u; return (float)c.h;
}

// async global->LDS, 16 B per lane; dest = lds base (wave-uniform) + lane*16
__device__ __forceinline__ void ld16(const ushort* g, ushort* l) {
    __builtin_amdgcn_global_load_lds(
        (const __attribute__((address_space(1))) unsigned int*)g,
        (__attribute__((address_space(3))) unsigned int*)l, 16, 0, 0);
}

__device__ __forceinline__ int lbound(const int* __restrict__ a, int n, int key) {
    int lo = 0, hi = n;
    while (lo < hi) { int mid = (lo + hi) >> 1; if (a[mid] < key) lo = mid + 1; else hi = mid; }
    return lo;
}

// ------------------------------------------------------------ edge sorting by (dst, etype)
__global__ void hist9_kernel(const int* __restrict__ dst, const int* __restrict__ ety,
                             int* __restrict__ cnt9) {
    int e = blockIdx.x * 256 + threadIdx.x;
    if (e < N_EDGES) atomicAdd(&cnt9[dst[e] * REL + ety[e]], 1);
}

// 8 elements per thread -> 8192 per block; NK9=900000 -> 110 blocks (fits scan2's 128)
__global__ void scan1_8(const int* __restrict__ cnt, int* __restrict__ excl,
                        int* __restrict__ bsum, int n) {
    __shared__ int s[1024];
    int tid = threadIdx.x;
    int base = blockIdx.x * 8192 + tid * 8;
    int v[8]; int sum = 0;
#pragma unroll
    for (int j = 0; j < 8; ++j) { v[j] = (base + j < n) ? cnt[base + j] : 0; sum += v[j]; }
    s[tid] = sum;
    __syncthreads();
    for (int off = 1; off < 1024; off <<= 1) {
        int t = (tid >= off) ? s[tid - off] : 0;
        __syncthreads();
        s[tid] += t;
        __syncthreads();
    }
    int run = s[tid] - sum;
#pragma unroll
    for (int j = 0; j < 8; ++j) { if (base + j < n) excl[base + j] = run; run += v[j]; }
    if (tid == 1023) bsum[blockIdx.x] = s[1023];
}

__global__ void scan2_kernel(int* __restrict__ bsum, int nb) {
    __shared__ int s[128];
    int tid = threadIdx.x;
    int v = (tid < nb) ? bsum[tid] : 0;
    s[tid] = v;
    __syncthreads();
    for (int off = 1; off < 128; off <<= 1) {
        int t = (tid >= off) ? s[tid - off] : 0;
        __syncthreads();
        s[tid] += t;
        __syncthreads();
    }
    if (tid < nb) bsum[tid] = s[tid] - v;
}

__global__ void scan3_8(int* __restrict__ excl, const int* __restrict__ bsum, int n, int total) {
    int base = blockIdx.x * 8192 + threadIdx.x * 8;
    int add = bsum[blockIdx.x];
#pragma unroll
    for (int j = 0; j < 8; ++j) if (base + j < n) excl[base + j] += add;
    if (blockIdx.x == 0 && threadIdx.x == 0) excl[n] = total;  // sentinel
}

// round 12: setp dropped — relation is derived in s_pass from rstart boundaries (RELOF,
// hardware-verified logic from rounds 2-4). One fewer scattered store here.
__global__ void scatter9_kernel(const int* __restrict__ src, const int* __restrict__ dst,
                                const int* __restrict__ ety, const int* __restrict__ rstart,
                                int* __restrict__ cur9, int* __restrict__ ssrc) {
    int e = blockIdx.x * 256 + threadIdx.x;
    if (e < N_EDGES) {
        int key = dst[e] * REL + ety[e];
        int pos = rstart[key] + atomicAdd(&cur9[key], 1);
        ssrc[pos] = src[e];
    }
}

// ------------------------------------------------------------- graph norm (moment form)
// Round 8 form (proven): float4 loads + 8 row-phases + per-block LDS reduction,
// ONE atomic pair per (group, channel, block).
__global__ __launch_bounds__(256)
void gn_stats(const float* __restrict__ x, const int* __restrict__ seg,
              float* __restrict__ gsum, float* __restrict__ gsumsq) {
    __shared__ float redS[8][128];
    __shared__ float redQ[8][128];
    int t = threadIdx.x;
    int c4 = (t & 31) * 4;           // 32 threads span 128 channels (float4 each)
    int rr = t >> 5;                 // 8 row-phases in flight
    int n0 = blockIdx.x * 128;
    int nend = min(n0 + 128, N_NODES);
    int len = nend - n0;
    int gfirst = seg[n0];
    int glast = seg[nend - 1];
    for (int g = gfirst; g <= glast; ++g) {
        int lo = (g == gfirst) ? n0 : n0 + lbound(seg + n0, len, g);
        int hi = (g == glast) ? nend : n0 + lbound(seg + n0, len, g + 1);
        float s0 = 0.f, s1 = 0.f, s2 = 0.f, s3 = 0.f;
        float q0 = 0.f, q1 = 0.f, q2 = 0.f, q3 = 0.f;
        for (int n = lo + rr; n < hi; n += 8) {
            float4 v = *(const float4*)&x[(size_t)n * D + c4];
            s0 += v.x; q0 += v.x * v.x;
            s1 += v.y; q1 += v.y * v.y;
            s2 += v.z; q2 += v.z * v.z;
            s3 += v.w; q3 += v.w * v.w;
        }
        redS[rr][c4 + 0] = s0; redS[rr][c4 + 1] = s1;
        redS[rr][c4 + 2] = s2; redS[rr][c4 + 3] = s3;
        redQ[rr][c4 + 0] = q0; redQ[rr][c4 + 1] = q1;
        redQ[rr][c4 + 2] = q2; redQ[rr][c4 + 3] = q3;
        __syncthreads();
        if (t < 128) {
            float ts = 0.f, tq = 0.f;
#pragma unroll
            for (int ph = 0; ph < 8; ++ph) { ts += redS[ph][t]; tq += redQ[ph][t]; }
            atomicAdd(&gsum[g * D + t], ts);
            atomicAdd(&gsumsq[g * D + t], tq);
        }
        __syncthreads();
    }
}

__global__ __launch_bounds__(256)
void gn_stats_h(const ushort* __restrict__ x, const int* __restrict__ seg,
                float* __restrict__ gsum, float* __restrict__ gsumsq) {
    __shared__ float redS[8][128];
    __shared__ float redQ[8][128];
    int t = threadIdx.x;
    int c4 = (t & 31) * 4;
    int rr = t >> 5;
    int n0 = blockIdx.x * 128;
    int nend = min(n0 + 128, N_NODES);
    int len = nend - n0;
    int gfirst = seg[n0];
    int glast = seg[nend - 1];
    for (int g = gfirst; g <= glast; ++g) {
        int lo = (g == gfirst) ? n0 : n0 + lbound(seg + n0, len, g);
        int hi = (g == glast) ? nend : n0 + lbound(seg + n0, len, g + 1);
        float s0 = 0.f, s1 = 0.f, s2 = 0.f, s3 = 0.f;
        float q0 = 0.f, q1 = 0.f, q2 = 0.f, q3 = 0.f;
        for (int n = lo + rr; n < hi; n += 8) {
            ushort4 u = *(const ushort4*)&x[(size_t)n * D + c4];
            float v0 = h2f(u.x), v1 = h2f(u.y), v2 = h2f(u.z), v3 = h2f(u.w);
            s0 += v0; q0 += v0 * v0;
            s1 += v1; q1 += v1 * v1;
            s2 += v2; q2 += v2 * v2;
            s3 += v3; q3 += v3 * v3;
        }
        redS[rr][c4 + 0] = s0; redS[rr][c4 + 1] = s1;
        redS[rr][c4 + 2] = s2; redS[rr][c4 + 3] = s3;
        redQ[rr][c4 + 0] = q0; redQ[rr][c4 + 1] = q1;
        redQ[rr][c4 + 2] = q2; redQ[rr][c4 + 3] = q3;
        __syncthreads();
        if (t < 128) {
            float ts = 0.f, tq = 0.f;
#pragma unroll
            for (int ph = 0; ph < 8; ++ph) { ts += redS[ph][t]; tq += redQ[ph][t]; }
            atomicAdd(&gsum[g * D + t], ts);
            atomicAdd(&gsumsq[g * D + t], tq);
        }
        __syncthreads();
    }
}

__global__ void gn_final(const float* __restrict__ gsum, const float* __restrict__ gsumsq,
                         const int* __restrict__ seg, const float* __restrict__ w,
                         const float* __restrict__ b, const float* __restrict__ ms,
                         float* __restrict__ sc, float* __restrict__ off) {
    int g = blockIdx.x, ch = threadIdx.x;
    int lo = lbound(seg, N_NODES, g), hi = lbound(seg, N_NODES, g + 1);
    float cnt = (float)max(hi - lo, 1);
    float mean = gsum[g * D + ch] / cnt;
    float mm = mean * ms[ch];
    float var = gsumsq[g * D + ch] / cnt - 2.f * mm * mean + mm * mm;
    float rstd = rsqrtf(var + 1e-6f);
    float s = w[ch] * rstd;
    sc[g * D + ch] = s;
    off[g * D + ch] = b[ch] - s * mm;
}

__global__ __launch_bounds__(256)
void gn_apply(const float* __restrict__ x, const int* __restrict__ seg,
              const float* __restrict__ sc, const float* __restrict__ off,
              ushort* __restrict__ outhf) {
    int t = blockIdx.x * 256 + threadIdx.x;
    int n = t >> 6;
    if (n >= N_NODES) return;
    int ch = (t & 63) * 2;
    int g = seg[n];
    float2 xv = *(const float2*)&x[(size_t)n * D + ch];
    float2 s2 = *(const float2*)&sc[g * D + ch];
    float2 o2 = *(const float2*)&off[g * D + ch];
    ushort2 o;
    o.x = f2h(s2.x * xv.x + o2.x);
    o.y = f2h(s2.y * xv.y + o2.y);
    *(ushort2*)&outhf[(size_t)n * D + ch] = o;
}

// ------------------------- combined QKV weight build (fp16, transposed), all 3 projections
__global__ void build_bt_qkv3(const float* __restrict__ c0, const float* __restrict__ c1,
                              const float* __restrict__ c2, const float* __restrict__ b0,
                              const float* __restrict__ b1, const float* __restrict__ b2,
                              const float* __restrict__ l0, const float* __restrict__ l1,
                              const float* __restrict__ l2, const float* __restrict__ i0,
                              const float* __restrict__ i1, const float* __restrict__ i2,
                              ushort* __restrict__ Btqkv, float* __restrict__ biasq) {
    int pj = blockIdx.y;
    const float* coeff  = pj == 0 ? c0 : (pj == 1 ? c1 : c2);
    const float* basis  = pj == 0 ? b0 : (pj == 1 ? b1 : b2);
    const float* loop_w = pj == 0 ? l0 : (pj == 1 ? l1 : l2);
    const float* bin    = pj == 0 ? i0 : (pj == 1 ? i1 : i2);
    ushort* Bt = Btqkv + (size_t)pj * 128 * 1280;
    int t = blockIdx.x * 256 + threadIdx.x;
    if (t < 128) biasq[pj * 128 + t] = bin[t];
    if (t >= 128 * 1280) return;
    int o = t / 1280;
    int k = t - o * 1280;
    float v;
    if (k < 128) {
        v = loop_w[k * 128 + o];
    } else {
        int kk = k - 128;
        int r = kk >> 7, i = kk & 127;
        v = 0.f;
#pragma unroll
        for (int b = 0; b < REL; ++b)
            v += coeff[r * REL + b] * basis[((size_t)b * 128 + i) * 128 + o];
    }
    Bt[(size_t)o * 1280 + k] = f2h(v);
}

// single launch for o_w / ffn1 / ffn2 transposed fp16 weights
__global__ void transpose_cast3(const float* __restrict__ o_w, ushort* __restrict__ Bto,
                                const float* __restrict__ f1, ushort* __restrict__ Btf1,
                                const float* __restrict__ f2, ushort* __restrict__ Btf2) {
    int t = blockIdx.x * 256 + threadIdx.x;
    if (t < 16384) {                 // o_w: I=128, O=128
        int n = t >> 7, k = t & 127;
        Bto[(size_t)n * 128 + k] = f2h(o_w[(size_t)k * 128 + n]);
    } else if (t < 49152) {          // ffn1: I=128, O=256
        int u = t - 16384;
        int n = u >> 7, k = u & 127;
        Btf1[(size_t)n * 128 + k] = f2h(f1[(size_t)k * 256 + n]);
    } else if (t < 81920) {          // ffn2: I=256, O=128
        int u = t - 49152;
        int n = u >> 8, k = u & 255;
        Btf2[(size_t)n * 256 + k] = f2h(f2[(size_t)k * 128 + n]);
    }
}

// ----------------------------------------- per-relation gathered sums -> Ab rows (fp16, 1152)
// half2 packed accumulation; 4-edge unroll (r9). Round 12: relation derived from the 8
// hoisted rstart boundaries (RELOF, verified r2-r4) — wave-uniform, removes the setp load
// from the critical path.
__global__ __launch_bounds__(256)
void s_pass(const ushort* __restrict__ hnhf, const int* __restrict__ ssrc,
            const int* __restrict__ rstart, ushort* __restrict__ Ab, int c0, int c1) {
    int n = c0 + ((blockIdx.x * 256 + threadIdx.x) >> 6);
    if (n >= c1) return;
    int lane = threadIdx.x & 63;
    const int* rp = rstart + n * REL;
    int e0 = rp[0];
    int rs1 = rp[1], rs2 = rp[2], rs3 = rp[3], rs4 = rp[4];
    int rs5 = rp[5], rs6 = rp[6], rs7 = rp[7], rs8 = rp[8];
    int e1 = rp[9];
    h16x2 a0 = (h16x2)0, a1 = (h16x2)0, a2 = (h16x2)0, a3 = (h16x2)0, a4 = (h16x2)0;
    h16x2 a5 = (h16x2)0, a6 = (h16x2)0, a7 = (h16x2)0, a8 = (h16x2)0;
#define RELOF(ee) (((ee) >= rs1) + ((ee) >= rs2) + ((ee) >= rs3) + ((ee) >= rs4) + \
                   ((ee) >= rs5) + ((ee) >= rs6) + ((ee) >= rs7) + ((ee) >= rs8))
#define ACC(rr, hv) switch (rr) { \
        case 0: a0 += hv; break; case 1: a1 += hv; break; case 2: a2 += hv; break; \
        case 3: a3 += hv; break; case 4: a4 += hv; break; case 5: a5 += hv; break; \
        case 6: a6 += hv; break; case 7: a7 += hv; break; default: a8 += hv; break; }
    int e = e0;
    for (; e + 4 <= e1; e += 4) {
        int s0 = ssrc[e], s1 = ssrc[e + 1], s2 = ssrc[e + 2], s3 = ssrc[e + 3];
        int r0 = RELOF(e), r1 = RELOF(e + 1), r2 = RELOF(e + 2), r3 = RELOF(e + 3);
        h16x2 hv0 = *(const h16x2*)&hnhf[(size_t)s0 * D + 2 * lane];
        h16x2 hv1 = *(const h16x2*)&hnhf[(size_t)s1 * D + 2 * lane];
        h16x2 hv2 = *(const h16x2*)&hnhf[(size_t)s2 * D + 2 * lane];
        h16x2 hv3 = *(const h16x2*)&hnhf[(size_t)s3 * D + 2 * lane];
        ACC(r0, hv0)
        ACC(r1, hv1)
        ACC(r2, hv2)
        ACC(r3, hv3)
    }
    for (; e < e1; ++e) {
        int s0 = ssrc[e];
        int r0 = RELOF(e);
        h16x2 hv0 = *(const h16x2*)&hnhf[(size_t)s0 * D + 2 * lane];
        ACC(r0, hv0)
    }
#undef ACC
#undef RELOF
    ushort* arow = Ab + (size_t)(n - c0) * 1152;
#define ST(r) *(h16x2*)&arow[r * 128 + 2 * lane] = a##r;
    ST(0) ST(1) ST(2) ST(3) ST(4) ST(5) ST(6) ST(7) ST(8)
#undef ST
}

// ---------------------------------------------------- QKV MFMA GEMM, full 384-col block
// Block = 128 rows x ALL 384 cols (A read ONCE).
// 512 threads, 8 waves (2 row-halves x 4 col-quarters), acc[4][6]; LDS 64 KB (2 blk/CU).
// K: 0..127 from hnhf (lda 128), 128..1279 from Ab (lda 1152, col k-128).
__global__ __launch_bounds__(512)
void mfma_gemm384(const ushort* __restrict__ A1, const ushort* __restrict__ Ab, int M,
                  const ushort* __restrict__ Bt, const float* __restrict__ bias,
                  ushort* __restrict__ Cout) {
    __shared__ ushort As[128 * 64];
    __shared__ ushort Bs[384 * 64];
    const int tid = threadIdx.x;
    const int lane = tid & 63;
    const int wave = tid >> 6;               // 0..7
    const int wm = wave & 1, wn = wave >> 1; // 2 row-halves x 4 col-quarters
    const int quad = lane >> 4, l16 = lane & 15;
    const int row0 = blockIdx.x * 128;

    const ushort* sA1[2];
    const ushort* sA2[2];
#pragma unroll
    for (int i = 0; i < 2; ++i) {
        int rs = (wave * 2 + i) * 8 + (lane >> 3);
        int kg = (lane & 7) ^ (rs & 7);
        int ra = row0 + rs; if (ra >= M) ra = M - 1;
        sA1[i] = A1 + (size_t)ra * 128 + kg * 8;
        sA2[i] = Ab + (size_t)ra * 1152 + kg * 8;
    }
    const ushort* sB[6];
#pragma unroll
    for (int i = 0; i < 6; ++i) {
        int rs = (wave * 6 + i) * 8 + (lane >> 3);
        int kg = (lane & 7) ^ (rs & 7);
        sB[i] = Bt + (size_t)rs * 1280 + kg * 8;
    }

    f32x4 acc[4][6];
#pragma unroll
    for (int i = 0; i < 4; ++i)
#pragma unroll
        for (int j = 0; j < 6; ++j) acc[i][j] = (f32x4){0.f, 0.f, 0.f, 0.f};

    for (int kc = 0; kc < 1280; kc += 64) {
#pragma unroll
        for (int i = 0; i < 6; ++i) ld16(sB[i] + kc, &Bs[(wave * 6 + i) * 512]);
#pragma unroll
        for (int i = 0; i < 2; ++i) {
            const ushort* as = (kc < 128) ? (sA1[i] + kc) : (sA2[i] + (kc - 128));
            ld16(as, &As[(wave * 2 + i) * 512]);
        }
        __syncthreads();
#pragma unroll
        for (int h = 0; h < 2; ++h) {
            f16x8 af[4], bf[6];
#pragma unroll
            for (int i = 0; i < 4; ++i) {
                int r = wm * 64 + i * 16 + l16;
                af[i] = *(const f16x8*)&As[r * 64 + (((h * 4 + quad) ^ (r & 7)) * 8)];
            }
#pragma unroll
            for (int j = 0; j < 6; ++j) {
                int c = wn * 96 + j * 16 + l16;
                bf[j] = *(const f16x8*)&Bs[c * 64 + (((h * 4 + quad) ^ (c & 7)) * 8)];
            }
#pragma unroll
            for (int i = 0; i < 4; ++i)
#pragma unroll
                for (int j = 0; j < 6; ++j)
                    acc[i][j] = __builtin_amdgcn_mfma_f32_16x16x32_f16(af[i], bf[j], acc[i][j], 0, 0, 0);
        }
        __syncthreads();
    }

#pragma unroll
    for (int i = 0; i < 4; ++i) {
        int gr0 = wm * 64 + i * 16 + quad * 4 + row0;
#pragma unroll
        for (int r = 0; r < 4; ++r) {
            int gr = gr0 + r;
            if (gr >= M) continue;
#pragma unroll
            for (int j = 0; j < 6; ++j) {
                int gcol = wn * 96 + j * 16 + l16;
                float v = acc[i][j][r] + bias[gcol];
                v = fmaxf(v, 0.f);
                Cout[(size_t)gr * 384 + gcol] = f2h(v);
            }
        }
    }
}

// ------------------------------------------------ fp16 MFMA GEMM + fused row LayerNorm
// (o-projection + ln1; 256 threads, 4 waves)
template<bool F16OUT>
__global__ __launch_bounds__(256, 3)
void mfma_gemm_ln(const ushort* __restrict__ A, int lda, int M,
                  const ushort* __restrict__ Bt, int K,
                  const float* __restrict__ bias, const float* __restrict__ lng,
                  const float* __restrict__ lnb, void* __restrict__ Cout) {
    __shared__ ushort As[128 * 64];
    __shared__ ushort Bs[128 * 64];
    __shared__ float rsum[2][128];
    __shared__ float rsq[2][128];
    const int tid = threadIdx.x;
    const int lane = tid & 63;
    const int wave = tid >> 6;
    const int wm = wave & 1, wn = wave >> 1;
    const int quad = lane >> 4, l16 = lane & 15;
    const int row0 = blockIdx.y * 128;

    const ushort* sA[4];
    const ushort* sB[4];
#pragma unroll
    for (int i = 0; i < 4; ++i) {
        int rs = (wave * 4 + i) * 8 + (lane >> 3);
        int kg = (lane & 7) ^ (rs & 7);
        int ra = row0 + rs; if (ra >= M) ra = M - 1;
        sA[i] = A + (size_t)ra * lda + kg * 8;
        sB[i] = Bt + (size_t)rs * K + kg * 8;
    }

    f32x4 acc[4][4];
#pragma unroll
    for (int i = 0; i < 4; ++i)
#pragma unroll
        for (int j = 0; j < 4; ++j) acc[i][j] = (f32x4){0.f, 0.f, 0.f, 0.f};

    for (int kc = 0; kc < K; kc += 64) {
#pragma unroll
        for (int i = 0; i < 4; ++i) {
            ld16(sA[i] + kc, &As[(wave * 4 + i) * 512]);
            ld16(sB[i] + kc, &Bs[(wave * 4 + i) * 512]);
        }
        __syncthreads();
#pragma unroll
        for (int h = 0; h < 2; ++h) {
            f16x8 af[4], bf[4];
#pragma unroll
            for (int i = 0; i < 4; ++i) {
                int r = wm * 64 + i * 16 + l16;
                af[i] = *(const f16x8*)&As[r * 64 + (((h * 4 + quad) ^ (r & 7)) * 8)];
                int c = wn * 64 + i * 16 + l16;
                bf[i] = *(const f16x8*)&Bs[c * 64 + (((h * 4 + quad) ^ (c & 7)) * 8)];
            }
#pragma unroll
            for (int i = 0; i < 4; ++i)
#pragma unroll
                for (int j = 0; j < 4; ++j)
                    acc[i][j] = __builtin_amdgcn_mfma_f32_16x16x32_f16(af[i], bf[j], acc[i][j], 0, 0, 0);
        }
        __syncthreads();
    }

#pragma unroll
    for (int i = 0; i < 4; ++i) {
#pragma unroll
        for (int r = 0; r < 4; ++r) {
            float s = 0.f, q = 0.f;
#pragma unroll
            for (int j = 0; j < 4; ++j) {
                float v = acc[i][j][r] + bias[wn * 64 + j * 16 + l16];
                s += v; q += v * v;
            }
            s += __shfl_xor(s, 1); q += __shfl_xor(q, 1);
            s += __shfl_xor(s, 2); q += __shfl_xor(q, 2);
            s += __shfl_xor(s, 4); q += __shfl_xor(q, 4);
            s += __shfl_xor(s, 8); q += __shfl_xor(q, 8);
            if (l16 == 0) {
                int row = wm * 64 + i * 16 + quad * 4 + r;
                rsum[wn][row] = s;
                rsq[wn][row] = q;
            }
        }
    }
    __syncthreads();

#pragma unroll
    for (int i = 0; i < 4; ++i) {
#pragma unroll
        for (int r = 0; r < 4; ++r) {
            int row = wm * 64 + i * 16 + quad * 4 + r;
            int grow = row0 + row;
            if (grow >= M) continue;
            float tot = rsum[0][row] + rsum[1][row];
            float tq  = rsq[0][row] + rsq[1][row];
            float mu = tot * (1.f / 128.f);
            float var = tq * (1.f / 128.f) - mu * mu;
            float rstd = rsqrtf(var + 1e-5f);
#pragma unroll
            for (int j = 0; j < 4; ++j) {
                int gcol = wn * 64 + j * 16 + l16;
                float v = acc[i][j][r] + bias[gcol];
                float o = lng[gcol] * (v - mu) * rstd + lnb[gcol];
                if (F16OUT) ((ushort*)Cout)[(size_t)grow * 128 + gcol] = f2h(o);
                else        ((float*)Cout)[(size_t)grow * 128 + gcol] = o;
            }
        }
    }
}

// ---------------------------------------------------------------- fused FFN v3 (round 12)
// r11 structure (64-row blocks, 75 KB LDS, 2 blk/CU, padded row-major C1s) + fused
// gn2-apply on the A staging path: A is reg-staged (load h1 fp16, apply per-group
// sc/off — bit-identical math to gn_apply_h — then ds_write to the exact LDS address
// ld16 used). Deletes the gn_apply_h dispatch and its 51 MB round trip.
__global__ __launch_bounds__(512)
void ffn_fused(const ushort* __restrict__ h1, const int* __restrict__ seg,
               const float* __restrict__ gsc, const float* __restrict__ goff, int M,
               const ushort* __restrict__ B1t, const float* __restrict__ b1,
               const ushort* __restrict__ B2t, const float* __restrict__ b2,
               const float* __restrict__ lng, const float* __restrict__ lnb,
               float* __restrict__ Cout) {
    extern __shared__ ushort sh[];
    ushort* As   = sh;                           // 64*64   =  8 KB
    ushort* Bs   = sh + 64 * 64;                 // 256*64  = 32 KB (phase1) / 128*64 (phase2)
    ushort* C1s  = sh + 64 * 64 + 256 * 64;      // 64*264  = 33 KB
    float*  rsum = (float*)(C1s + 64 * C1LD);    // [4][64]
    float*  rsq  = rsum + 4 * 64;
    const int tid = threadIdx.x;
    const int lane = tid & 63;
    const int wave = tid >> 6;               // 0..7
    const int wm = wave & 1, wn = wave >> 1; // 2 row-halves(32) x 4 col groups
    const int quad = lane >> 4, l16 = lane & 15;
    const int row0 = blockIdx.x * 64;

    // ---------------- phase 1: C1 = relu(gn2(h1) x B1t + b1), 64x256, K=128
    {
        int rsA = wave * 8 + (lane >> 3);
        int kgA = (lane & 7) ^ (rsA & 7);
        int raA = row0 + rsA; if (raA >= M) raA = M - 1;
        int gA = seg[raA];
        const ushort* srcA = h1 + (size_t)raA * 128 + kgA * 8;
        const float*  scp  = gsc + gA * 128 + kgA * 8;
        const float*  offp = goff + gA * 128 + kgA * 8;
        ushort* dstA = &As[wave * 512 + lane * 8];   // = ld16's dest (base + lane*16 B)
        const ushort* sB[4];
#pragma unroll
        for (int i = 0; i < 4; ++i) {
            int rs = (wave * 4 + i) * 8 + (lane >> 3);
            int kg = (lane & 7) ^ (rs & 7);
            sB[i] = B1t + (size_t)rs * 128 + kg * 8;
        }
        f32x4 acc[2][4];
#pragma unroll
        for (int i = 0; i < 2; ++i)
#pragma unroll
            for (int j = 0; j < 4; ++j) acc[i][j] = (f32x4){0.f, 0.f, 0.f, 0.f};

        for (int kc = 0; kc < 128; kc += 64) {
#pragma unroll
            for (int i = 0; i < 4; ++i) ld16(sB[i] + kc, &Bs[(wave * 4 + i) * 512]);
            // reg-staged A with fused gn2-apply
            {
                ushort4 u0 = *(const ushort4*)(srcA + kc);
                ushort4 u1 = *(const ushort4*)(srcA + kc + 4);
                float4 sc0 = *(const float4*)(scp + kc);
                float4 sc1 = *(const float4*)(scp + kc + 4);
                float4 of0 = *(const float4*)(offp + kc);
                float4 of1 = *(const float4*)(offp + kc + 4);
                f16x8 av;
                av[0] = (_Float16)(sc0.x * h2f(u0.x) + of0.x);
                av[1] = (_Float16)(sc0.y * h2f(u0.y) + of0.y);
                av[2] = (_Float16)(sc0.z * h2f(u0.z) + of0.z);
                av[3] = (_Float16)(sc0.w * h2f(u0.w) + of0.w);
                av[4] = (_Float16)(sc1.x * h2f(u1.x) + of1.x);
                av[5] = (_Float16)(sc1.y * h2f(u1.y) + of1.y);
                av[6] = (_Float16)(sc1.z * h2f(u1.z) + of1.z);
                av[7] = (_Float16)(sc1.w * h2f(u1.w) + of1.w);
                *(f16x8*)dstA = av;
            }
            __syncthreads();
#pragma unroll
            for (int h = 0; h < 2; ++h) {
                f16x8 af[2], bf[4];
#pragma unroll
                for (int i = 0; i < 2; ++i) {
                    int r = wm * 32 + i * 16 + l16;
                    af[i] = *(const f16x8*)&As[r * 64 + (((h * 4 + quad) ^ (r & 7)) * 8)];
                }
#pragma unroll
                for (int j = 0; j < 4; ++j) {
                    int c = wn * 64 + j * 16 + l16;
                    bf[j] = *(const f16x8*)&Bs[c * 64 + (((h * 4 + quad) ^ (c & 7)) * 8)];
                }
#pragma unroll
                for (int i = 0; i < 2; ++i)
#pragma unroll
                    for (int j = 0; j < 4; ++j)
                        acc[i][j] = __builtin_amdgcn_mfma_f32_16x16x32_f16(af[i], bf[j], acc[i][j], 0, 0, 0);
            }
            __syncthreads();
        }

        // epilogue: relu + bias -> C1s (row-major, +8 pad); conflict-free stores.
#pragma unroll
        for (int i = 0; i < 2; ++i) {
            int lr0 = wm * 32 + i * 16 + quad * 4;
#pragma unroll
            for (int r = 0; r < 4; ++r) {
                int row = lr0 + r;
#pragma unroll
                for (int j = 0; j < 4; ++j) {
                    int col = wn * 64 + j * 16 + l16;
                    float v = acc[i][j][r] + b1[col];
                    v = fmaxf(v, 0.f);
                    C1s[row * C1LD + col] = f2h(v);
                }
            }
        }
    }
    __syncthreads();

    // ---------------- phase 2: C2 = C1 x B2t + b2 (+row-LN), 64x128, K=256
    {
        const ushort* sB[2];
#pragma unroll
        for (int i = 0; i < 2; ++i) {
            int rs = (wave * 2 + i) * 8 + (lane >> 3);
            int kg = (lane & 7) ^ (rs & 7);
            sB[i] = B2t + (size_t)rs * 256 + kg * 8;
        }
        f32x4 acc[2][2];
#pragma unroll
        for (int i = 0; i < 2; ++i)
#pragma unroll
            for (int j = 0; j < 2; ++j) acc[i][j] = (f32x4){0.f, 0.f, 0.f, 0.f};

        for (int kc = 0; kc < 256; kc += 64) {
#pragma unroll
            for (int i = 0; i < 2; ++i) ld16(sB[i] + kc, &Bs[(wave * 2 + i) * 512]);
            __syncthreads();
#pragma unroll
            for (int h = 0; h < 2; ++h) {
                f16x8 af[2], bf[2];
#pragma unroll
                for (int i = 0; i < 2; ++i) {
                    int r = wm * 32 + i * 16 + l16;
                    af[i] = *(const f16x8*)&C1s[r * C1LD + kc + ((h * 4 + quad) * 8)];
                }
#pragma unroll
                for (int j = 0; j < 2; ++j) {
                    int c = wn * 32 + j * 16 + l16;
                    bf[j] = *(const f16x8*)&Bs[c * 64 + (((h * 4 + quad) ^ (c & 7)) * 8)];
                }
#pragma unroll
                for (int i = 0; i < 2; ++i)
#pragma unroll
                    for (int j = 0; j < 2; ++j)
                        acc[i][j] = __builtin_amdgcn_mfma_f32_16x16x32_f16(af[i], bf[j], acc[i][j], 0, 0, 0);
            }
            __syncthreads();
        }

        // row-LN across the 4 col groups
#pragma unroll
        for (int i = 0; i < 2; ++i) {
#pragma unroll
            for (int r = 0; r < 4; ++r) {
                float s = 0.f, q = 0.f;
#pragma unroll
                for (int j = 0; j < 2; ++j) {
                    float v = acc[i][j][r] + b2[wn * 32 + j * 16 + l16];
                    s += v; q += v * v;
                }
                s += __shfl_xor(s, 1); q += __shfl_xor(q, 1);
                s += __shfl_xor(s, 2); q += __shfl_xor(q, 2);
                s += __shfl_xor(s, 4); q += __shfl_xor(q, 4);
                s += __shfl_xor(s, 8); q += __shfl_xor(q, 8);
                if (l16 == 0) {
                    int row = wm * 32 + i * 16 + quad * 4 + r;
                    rsum[wn * 64 + row] = s;
                    rsq[wn * 64 + row] = q;
                }
            }
        }
        __syncthreads();

#pragma unroll
        for (int i = 0; i < 2; ++i) {
#pragma unroll
            for (int r = 0; r < 4; ++r) {
                int row = wm * 32 + i * 16 + quad * 4 + r;
                int grow = row0 + row;
                if (grow >= M) continue;
                float tot = rsum[row] + rsum[64 + row] + rsum[128 + row] + rsum[192 + row];
                float tq  = rsq[row] + rsq[64 + row] + rsq[128 + row] + rsq[192 + row];
                float mu = tot * (1.f / 128.f);
                float var = tq * (1.f / 128.f) - mu * mu;
                float rstd = rsqrtf(var + 1e-5f);
#pragma unroll
                for (int j = 0; j < 2; ++j) {
                    int gcol = wn * 32 + j * 16 + l16;
                    float v = acc[i][j][r] + b2[gcol];
                    float o = lng[gcol] * (v - mu) * rstd + lnb[gcol];
                    Cout[(size_t)grow * 128 + gcol] = o;
                }
            }
        }
    }
}

// --------------------------------------------------------------- attention
// 8-edge unroll (proven r9); at gather-BW plateau (~3.5 TB/s) — don't touch.
__global__ __launch_bounds__(256)
void attn_kernel(const ushort* __restrict__ C, const int* __restrict__ ssrc,
                 const int* __restrict__ rstart, ushort* __restrict__ attnhf) {
    int n = (blockIdx.x * 256 + threadIdx.x) >> 6;
    if (n >= N_NODES) return;
    int lane = threadIdx.x & 63;
    h16x2 qh = *(const h16x2*)&C[(size_t)n * 384 + 2 * lane];
    int e0 = rstart[n * REL], e1 = rstart[n * REL + REL];
    float wvx = 0.f, wvy = 0.f, z = 0.f;
    int e = e0;
    for (; e + 8 <= e1; e += 8) {
        int s[8];
#pragma unroll
        for (int j = 0; j < 8; ++j) s[j] = ssrc[e + j];
        h16x2 kk[8], vv[8];
#pragma unroll
        for (int j = 0; j < 8; ++j) kk[j] = *(const h16x2*)&C[(size_t)s[j] * 384 + 128 + 2 * lane];
#pragma unroll
        for (int j = 0; j < 8; ++j) vv[j] = *(const h16x2*)&C[(size_t)s[j] * 384 + 256 + 2 * lane];
        float d[8];
#pragma unroll
        for (int j = 0; j < 8; ++j) d[j] = __builtin_amdgcn_fdot2(kk[j], qh, 0.f, false);
#pragma unroll
        for (int j = 0; j < 8; ++j) d[j] += __shfl_xor(d[j], 1);
#pragma unroll
        for (int j = 0; j < 8; ++j) d[j] += __shfl_xor(d[j], 2);
#pragma unroll
        for (int j = 0; j < 8; ++j) d[j] += __shfl_xor(d[j], 4);
#pragma unroll
        for (int j = 0; j < 8; ++j) {
            float sc = __expf(fminf(fmaxf(d[j] * 0.25f, -10.f), 10.f));
            wvx += sc * (float)vv[j].x;
            wvy += sc * (float)vv[j].y;
            z += sc;
        }
    }
    for (; e + 4 <= e1; e += 4) {
        int s0 = ssrc[e], s1 = ssrc[e + 1], s2 = ssrc[e + 2], s3 = ssrc[e + 3];
        h16x2 k0 = *(const h16x2*)&C[(size_t)s0 * 384 + 128 + 2 * lane];
        h16x2 k1 = *(const h16x2*)&C[(size_t)s1 * 384 + 128 + 2 * lane];
        h16x2 k2 = *(const h16x2*)&C[(size_t)s2 * 384 + 128 + 2 * lane];
        h16x2 k3 = *(const h16x2*)&C[(size_t)s3 * 384 + 128 + 2 * lane];
        h16x2 v0 = *(const h16x2*)&C[(size_t)s0 * 384 + 256 + 2 * lane];
        h16x2 v1 = *(const h16x2*)&C[(size_t)s1 * 384 + 256 + 2 * lane];
        h16x2 v2 = *(const h16x2*)&C[(size_t)s2 * 384 + 256 + 2 * lane];
        h16x2 v3 = *(const h16x2*)&C[(size_t)s3 * 384 + 256 + 2 * lane];
        float d0 = __builtin_amdgcn_fdot2(k0, qh, 0.f, false);
        float d1 = __builtin_amdgcn_fdot2(k1, qh, 0.f, false);
        float d2 = __builtin_amdgcn_fdot2(k2, qh, 0.f, false);
        float d3 = __builtin_amdgcn_fdot2(k3, qh, 0.f, false);
        d0 += __shfl_xor(d0, 1); d1 += __shfl_xor(d1, 1);
        d2 += __shfl_xor(d2, 1); d3 += __shfl_xor(d3, 1);
        d0 += __shfl_xor(d0, 2); d1 += __shfl_xor(d1, 2);
        d2 += __shfl_xor(d2, 2); d3 += __shfl_xor(d3, 2);
        d0 += __shfl_xor(d0, 4); d1 += __shfl_xor(d1, 4);
        d2 += __shfl_xor(d2, 4); d3 += __shfl_xor(d3, 4);
        float sc0 = __expf(fminf(fmaxf(d0 * 0.25f, -10.f), 10.f));
        float sc1 = __expf(fminf(fmaxf(d1 * 0.25f, -10.f), 10.f));
        float sc2 = __expf(fminf(fmaxf(d2 * 0.25f, -10.f), 10.f));
        float sc3 = __expf(fminf(fmaxf(d3 * 0.25f, -10.f), 10.f));
        wvx += sc0 * (float)v0.x + sc1 * (float)v1.x;
        wvy += sc0 * (float)v0.y + sc1 * (float)v1.y;
        wvx += sc2 * (float)v2.x + sc3 * (float)v3.x;
        wvy += sc2 * (float)v2.y + sc3 * (float)v3.y;
        z += sc0 + sc1 + sc2 + sc3;
    }
    for (; e < e1; ++e) {
        int s0 = ssrc[e];
        h16x2 k0 = *(const h16x2*)&C[(size_t)s0 * 384 + 128 + 2 * lane];
        h16x2 v0 = *(const h16x2*)&C[(size_t)s0 * 384 + 256 + 2 * lane];
        float d0 = __builtin_amdgcn_fdot2(k0, qh, 0.f, false);
        d0 += __shfl_xor(d0, 1);
        d0 += __shfl_xor(d0, 2);
        d0 += __shfl_xor(d0, 4);
        float sc0 = __expf(fminf(fmaxf(d0 * 0.25f, -10.f), 10.f));
        wvx += sc0 * (float)v0.x;
        wvy += sc0 * (float)v0.y;
        z += sc0;
    }
    float inv = 1.f / (z + 1e-6f);
    ushort2 o;
    o.x = f2h(wvx * inv);
    o.y = f2h(wvy * inv);
    *(ushort2*)&attnhf[(size_t)n * D + 2 * lane] = o;
}

// ------------------------------------------------------------------ launch
extern "C" void kernel_launch(void* const* d_in, const int* in_sizes, int n_in,
                              void* d_out, int out_size, void* d_ws, size_t ws_size,
                              hipStream_t stream) {
    (void)in_sizes; (void)n_in; (void)out_size;
    const float* h     = (const float*)d_in[0];
    const int*   src   = (const int*)d_in[1];
    const int*   dst   = (const int*)d_in[2];
    const int*   ety   = (const int*)d_in[3];
    const int*   seg   = (const int*)d_in[4];
    const float* coeffs[3] = {(const float*)d_in[6],  (const float*)d_in[10], (const float*)d_in[14]};
    const float* bases [3] = {(const float*)d_in[7],  (const float*)d_in[11], (const float*)d_in[15]};
    const float* loops [3] = {(const float*)d_in[8],  (const float*)d_in[12], (const float*)d_in[16]};
    const float* pbias [3] = {(const float*)d_in[9],  (const float*)d_in[13], (const float*)d_in[17]};
    const float* o_w   = (const float*)d_in[18];
    const float* o_b   = (const float*)d_in[19];
    const float* gn1_w = (const float*)d_in[20];
    const float* gn1_b = (const float*)d_in[21];
    const float* gn1_ms= (const float*)d_in[22];
    const float* gn2_w = (const float*)d_in[23];
    const float* gn2_b = (const float*)d_in[24];
    const float* gn2_ms= (const float*)d_in[25];
    const float* ln1_g = (const float*)d_in[26];
    const float* ln1_b = (const float*)d_in[27];
    const float* ln2_g = (const float*)d_in[28];
    const float* ln2_b = (const float*)d_in[29];
    const float* ffn1_w= (const float*)d_in[30];
    const float* ffn1_b= (const float*)d_in[31];
    const float* ffn2_w= (const float*)d_in[32];
    const float* ffn2_b= (const float*)d_in[33];

    char* p = (char*)d_ws;
    auto take = [&](size_t bytes) { char* r = p; p += (bytes + 255) & ~(size_t)255; return r; };
    int*    cnt9   = (int*)take((size_t)NK9 * 2 * 4);   // cnt9 + cur9, single memset
    int*    cur9   = cnt9 + NK9;
    int*    rstart = (int*)take((size_t)(NK9 + 8) * 4); // +sentinel
    int*    bsum   = (int*)take(512);
    int*    ssrc   = (int*)take((size_t)N_EDGES * 4);
    float*  gsum   = (float*)take((size_t)NG * D * 4 * 2);
    float*  gsumsq = gsum + NG * D;
    float*  gsc    = (float*)take((size_t)NG * D * 4);
    float*  goff   = (float*)take((size_t)NG * D * 4);
    ushort* Btqkv  = (ushort*)take((size_t)384 * 1280 * 2);
    float*  biasq  = (float*)take(384 * 4);
    ushort* Bto    = (ushort*)take((size_t)128 * 128 * 2);
    ushort* Btf1   = (ushort*)take((size_t)256 * 128 * 2);
    ushort* Btf2   = (ushort*)take((size_t)128 * 256 * 2);
    ushort* hnhf   = (ushort*)take((size_t)N_NODES * D * 2);     // 25.6 MB
    ushort* attnhf = (ushort*)take((size_t)N_NODES * D * 2);     // 25.6 MB
    ushort* h1hf   = (ushort*)take((size_t)N_NODES * D * 2);     // 25.6 MB
    ushort* Cqkv   = (ushort*)take((size_t)N_NODES * 384 * 2);   // 76.8 MB
    size_t used = (size_t)(p - (char*)d_ws);
    size_t avail = (ws_size > used) ? ws_size - used : 0;
    int NC = 1;
    if (avail < (size_t)N_NODES * 1152 * 2) NC = 4;
    if (NC == 4 && avail < ((size_t)(N_NODES / 4 + 1) * 1152 * 2)) NC = 8;
    ushort* Ab = (ushort*)p;
    const int chunk = (N_NODES + NC - 1) / NC;

    const int EB = (N_EDGES + 255) / 256;
    const int KB = (NK9 + 8191) / 8192;               // 110 blocks <= scan2's 128
    const int WB = (N_NODES * 64 + 255) / 256;
    const int GB = (N_NODES + 127) / 128;
    const int RB = (N_NODES + 127) / 128;
    const int FB = (N_NODES + 63) / 64;

    // ---- sort edges by (dst, etype)
    hipMemsetAsync(cnt9, 0, (size_t)NK9 * 8, stream);  // cnt9 + cur9
    hist9_kernel<<<EB, 256, 0, stream>>>(dst, ety, cnt9);
    scan1_8<<<KB, 1024, 0, stream>>>(cnt9, rstart, bsum, NK9);
    scan2_kernel<<<1, 128, 0, stream>>>(bsum, KB);
    scan3_8<<<KB, 1024, 0, stream>>>(rstart, bsum, NK9, N_EDGES);
    scatter9_kernel<<<EB, 256, 0, stream>>>(src, dst, ety, rstart, cur9, ssrc);

    // ---- weights (2 dispatches total)
    build_bt_qkv3<<<dim3(640, 3), 256, 0, stream>>>(
        coeffs[0], coeffs[1], coeffs[2], bases[0], bases[1], bases[2],
        loops[0], loops[1], loops[2], pbias[0], pbias[1], pbias[2], Btqkv, biasq);
    transpose_cast3<<<320, 256, 0, stream>>>(o_w, Bto, ffn1_w, Btf1, ffn2_w, Btf2);

    // ---- graph norm 1 -> hnhf (fp16)
    hipMemsetAsync(gsum, 0, (size_t)NG * D * 8, stream);
    gn_stats<<<GB, 256, 0, stream>>>(h, seg, gsum, gsumsq);
    gn_final<<<NG, 128, 0, stream>>>(gsum, gsumsq, seg, gn1_w, gn1_b, gn1_ms, gsc, goff);
    gn_apply<<<WB, 256, 0, stream>>>(h, seg, gsc, goff, hnhf);

    // ---- QKV: S-pass + full-width (384-col) MFMA GEMM per chunk -> Cqkv (fp16)
    for (int c = 0; c < NC; ++c) {
        int c0 = c * chunk;
        int c1 = min(N_NODES, c0 + chunk);
        int rows = c1 - c0;
        if (rows <= 0) break;
        s_pass<<<(rows + 3) / 4, 256, 0, stream>>>(hnhf, ssrc, rstart, Ab, c0, c1);
        mfma_gemm384<<<(rows + 127) / 128, 512, 0, stream>>>(
            hnhf + (size_t)c0 * 128, Ab, rows, Btqkv, biasq, Cqkv + (size_t)c0 * 384);
    }

    // ---- attention -> attnhf (fp16); Cqkv dead after this
    attn_kernel<<<WB, 256, 0, stream>>>(Cqkv, ssrc, rstart, attnhf);

    // ---- output projection + fused ln1 -> h1hf (fp16)
    mfma_gemm_ln<true><<<dim3(1, RB), 256, 0, stream>>>(
        attnhf, 128, N_NODES, Bto, 128, o_b, ln1_g, ln1_b, h1hf);

    // ---- graph norm 2: stats + final only; apply is fused into ffn_fused's A staging
    hipMemsetAsync(gsum, 0, (size_t)NG * D * 8, stream);
    gn_stats_h<<<GB, 256, 0, stream>>>(h1hf, seg, gsum, gsumsq);
    gn_final<<<NG, 128, 0, stream>>>(gsum, gsumsq, seg, gn2_w, gn2_b, gn2_ms, gsc, goff);

    // ---- fused FFN v3: relu(gn2(h1) x W1 + b1) x W2 + b2, + ln2 -> d_out (fp32)
    const int FFN_LDS = (64 * 64 + 256 * 64 + 64 * C1LD) * 2 + 2 * 4 * 64 * 4;  // 76800
    hipFuncSetAttribute((const void*)ffn_fused, hipFuncAttributeMaxDynamicSharedMemorySize, FFN_LDS);
    ffn_fused<<<FB, 512, FFN_LDS, stream>>>(
        h1hf, seg, gsc, goff, N_NODES, Btf1, ffn1_b, Btf2, ffn2_b, ln2_g, ln2_b, (float*)d_out);
}

// Round 13
// 700.331 us; speedup vs baseline: 1.0721x; 1.0060x over previous
//
#include <hip/hip_runtime.h>
#include <math.h>

#define N_NODES 100000
#define N_EDGES 600000
#define D 128
#define REL 9
#define NG 64
#define NK9 (N_NODES * REL)
#define C1LD 264  // 256 + 8 pad (ushorts): row stride 528 B -> bank stride 4 -> 2-way (free)

typedef float f32x4 __attribute__((ext_vector_type(4)));
typedef _Float16 f16x8 __attribute__((ext_vector_type(8)));
typedef _Float16 h16x2 __attribute__((ext_vector_type(2)));

__device__ __forceinline__ ushort f2h(float x) {
    union { _Float16 h; ushort u; } c; c.h = (_Float16)x; return c.u;
}
__device__ __forceinline__ float h2f(ushort u) {
    union { ushort u; _Float16 h; } c; c.u = u; return (float)c.h;
}

// async global->LDS, 16 B per lane; dest = lds base (wave-uniform) + lane*16
__device__ __forceinline__ void ld16(const ushort* g, ushort* l) {
    __builtin_amdgcn_global_load_lds(
        (const __attribute__((address_space(1))) unsigned int*)g,
        (__attribute__((address_space(3))) unsigned int*)l, 16, 0, 0);
}

__device__ __forceinline__ int lbound(const int* __restrict__ a, int n, int key) {
    int lo = 0, hi = n;
    while (lo < hi) { int mid = (lo + hi) >> 1; if (a[mid] < key) lo = mid + 1; else hi = mid; }
    return lo;
}

// ------------------------------------------------------------ edge sorting by (dst, etype)
__global__ void hist9_kernel(const int* __restrict__ dst, const int* __restrict__ ety,
                             int* __restrict__ cnt9) {
    int e = blockIdx.x * 256 + threadIdx.x;
    if (e < N_EDGES) atomicAdd(&cnt9[dst[e] * REL + ety[e]], 1);
}

// 8 elements per thread -> 8192 per block; NK9=900000 -> 110 blocks (fits scan2's 128)
__global__ void scan1_8(const int* __restrict__ cnt, int* __restrict__ excl,
                        int* __restrict__ bsum, int n) {
    __shared__ int s[1024];
    int tid = threadIdx.x;
    int base = blockIdx.x * 8192 + tid * 8;
    int v[8]; int sum = 0;
#pragma unroll
    for (int j = 0; j < 8; ++j) { v[j] = (base + j < n) ? cnt[base + j] : 0; sum += v[j]; }
    s[tid] = sum;
    __syncthreads();
    for (int off = 1; off < 1024; off <<= 1) {
        int t = (tid >= off) ? s[tid - off] : 0;
        __syncthreads();
        s[tid] += t;
        __syncthreads();
    }
    int run = s[tid] - sum;
#pragma unroll
    for (int j = 0; j < 8; ++j) { if (base + j < n) excl[base + j] = run; run += v[j]; }
    if (tid == 1023) bsum[blockIdx.x] = s[1023];
}

__global__ void scan2_kernel(int* __restrict__ bsum, int nb) {
    __shared__ int s[128];
    int tid = threadIdx.x;
    int v = (tid < nb) ? bsum[tid] : 0;
    s[tid] = v;
    __syncthreads();
    for (int off = 1; off < 128; off <<= 1) {
        int t = (tid >= off) ? s[tid - off] : 0;
        __syncthreads();
        s[tid] += t;
        __syncthreads();
    }
    if (tid < nb) bsum[tid] = s[tid] - v;
}

__global__ void scan3_8(int* __restrict__ excl, const int* __restrict__ bsum, int n, int total) {
    int base = blockIdx.x * 8192 + threadIdx.x * 8;
    int add = bsum[blockIdx.x];
#pragma unroll
    for (int j = 0; j < 8; ++j) if (base + j < n) excl[base + j] += add;
    if (blockIdx.x == 0 && threadIdx.x == 0) excl[n] = total;  // sentinel
}

__global__ void scatter9_kernel(const int* __restrict__ src, const int* __restrict__ dst,
                                const int* __restrict__ ety, const int* __restrict__ rstart,
                                int* __restrict__ cur9, int* __restrict__ ssrc) {
    int e = blockIdx.x * 256 + threadIdx.x;
    if (e < N_EDGES) {
        int key = dst[e] * REL + ety[e];
        int pos = rstart[key] + atomicAdd(&cur9[key], 1);
        ssrc[pos] = src[e];
    }
}

// ------------------------------------------------------------- graph norm (moment form)
// Round 8 form (proven): float4 loads + 8 row-phases + per-block LDS reduction,
// ONE atomic pair per (group, channel, block).
__global__ __launch_bounds__(256)
void gn_stats(const float* __restrict__ x, const int* __restrict__ seg,
              float* __restrict__ gsum, float* __restrict__ gsumsq) {
    __shared__ float redS[8][128];
    __shared__ float redQ[8][128];
    int t = threadIdx.x;
    int c4 = (t & 31) * 4;           // 32 threads span 128 channels (float4 each)
    int rr = t >> 5;                 // 8 row-phases in flight
    int n0 = blockIdx.x * 128;
    int nend = min(n0 + 128, N_NODES);
    int len = nend - n0;
    int gfirst = seg[n0];
    int glast = seg[nend - 1];
    for (int g = gfirst; g <= glast; ++g) {
        int lo = (g == gfirst) ? n0 : n0 + lbound(seg + n0, len, g);
        int hi = (g == glast) ? nend : n0 + lbound(seg + n0, len, g + 1);
        float s0 = 0.f, s1 = 0.f, s2 = 0.f, s3 = 0.f;
        float q0 = 0.f, q1 = 0.f, q2 = 0.f, q3 = 0.f;
        for (int n = lo + rr; n < hi; n += 8) {
            float4 v = *(const float4*)&x[(size_t)n * D + c4];
            s0 += v.x; q0 += v.x * v.x;
            s1 += v.y; q1 += v.y * v.y;
            s2 += v.z; q2 += v.z * v.z;
            s3 += v.w; q3 += v.w * v.w;
        }
        redS[rr][c4 + 0] = s0; redS[rr][c4 + 1] = s1;
        redS[rr][c4 + 2] = s2; redS[rr][c4 + 3] = s3;
        redQ[rr][c4 + 0] = q0; redQ[rr][c4 + 1] = q1;
        redQ[rr][c4 + 2] = q2; redQ[rr][c4 + 3] = q3;
        __syncthreads();
        if (t < 128) {
            float ts = 0.f, tq = 0.f;
#pragma unroll
            for (int ph = 0; ph < 8; ++ph) { ts += redS[ph][t]; tq += redQ[ph][t]; }
            atomicAdd(&gsum[g * D + t], ts);
            atomicAdd(&gsumsq[g * D + t], tq);
        }
        __syncthreads();
    }
}

__global__ void gn_final(const float* __restrict__ gsum, const float* __restrict__ gsumsq,
                         const int* __restrict__ seg, const float* __restrict__ w,
                         const float* __restrict__ b, const float* __restrict__ ms,
                         float* __restrict__ sc, float* __restrict__ off) {
    int g = blockIdx.x, ch = threadIdx.x;
    int lo = lbound(seg, N_NODES, g), hi = lbound(seg, N_NODES, g + 1);
    float cnt = (float)max(hi - lo, 1);
    float mean = gsum[g * D + ch] / cnt;
    float mm = mean * ms[ch];
    float var = gsumsq[g * D + ch] / cnt - 2.f * mm * mean + mm * mm;
    float rstd = rsqrtf(var + 1e-6f);
    float s = w[ch] * rstd;
    sc[g * D + ch] = s;
    off[g * D + ch] = b[ch] - s * mm;
}

__global__ __launch_bounds__(256)
void gn_apply(const float* __restrict__ x, const int* __restrict__ seg,
              const float* __restrict__ sc, const float* __restrict__ off,
              ushort* __restrict__ outhf) {
    int t = blockIdx.x * 256 + threadIdx.x;
    int n = t >> 6;
    if (n >= N_NODES) return;
    int ch = (t & 63) * 2;
    int g = seg[n];
    float2 xv = *(const float2*)&x[(size_t)n * D + ch];
    float2 s2 = *(const float2*)&sc[g * D + ch];
    float2 o2 = *(const float2*)&off[g * D + ch];
    ushort2 o;
    o.x = f2h(s2.x * xv.x + o2.x);
    o.y = f2h(s2.y * xv.y + o2.y);
    *(ushort2*)&outhf[(size_t)n * D + ch] = o;
}

// ------------------------- combined QKV weight build (fp16, transposed), all 3 projections
__global__ void build_bt_qkv3(const float* __restrict__ c0, const float* __restrict__ c1,
                              const float* __restrict__ c2, const float* __restrict__ b0,
                              const float* __restrict__ b1, const float* __restrict__ b2,
                              const float* __restrict__ l0, const float* __restrict__ l1,
                              const float* __restrict__ l2, const float* __restrict__ i0,
                              const float* __restrict__ i1, const float* __restrict__ i2,
                              ushort* __restrict__ Btqkv, float* __restrict__ biasq) {
    int pj = blockIdx.y;
    const float* coeff  = pj == 0 ? c0 : (pj == 1 ? c1 : c2);
    const float* basis  = pj == 0 ? b0 : (pj == 1 ? b1 : b2);
    const float* loop_w = pj == 0 ? l0 : (pj == 1 ? l1 : l2);
    const float* bin    = pj == 0 ? i0 : (pj == 1 ? i1 : i2);
    ushort* Bt = Btqkv + (size_t)pj * 128 * 1280;
    int t = blockIdx.x * 256 + threadIdx.x;
    if (t < 128) biasq[pj * 128 + t] = bin[t];
    if (t >= 128 * 1280) return;
    int o = t / 1280;
    int k = t - o * 1280;
    float v;
    if (k < 128) {
        v = loop_w[k * 128 + o];
    } else {
        int kk = k - 128;
        int r = kk >> 7, i = kk & 127;
        v = 0.f;
#pragma unroll
        for (int b = 0; b < REL; ++b)
            v += coeff[r * REL + b] * basis[((size_t)b * 128 + i) * 128 + o];
    }
    Bt[(size_t)o * 1280 + k] = f2h(v);
}

// single launch for o_w / ffn1 / ffn2 transposed fp16 weights
__global__ void transpose_cast3(const float* __restrict__ o_w, ushort* __restrict__ Bto,
                                const float* __restrict__ f1, ushort* __restrict__ Btf1,
                                const float* __restrict__ f2, ushort* __restrict__ Btf2) {
    int t = blockIdx.x * 256 + threadIdx.x;
    if (t < 16384) {                 // o_w: I=128, O=128
        int n = t >> 7, k = t & 127;
        Bto[(size_t)n * 128 + k] = f2h(o_w[(size_t)k * 128 + n]);
    } else if (t < 49152) {          // ffn1: I=128, O=256
        int u = t - 16384;
        int n = u >> 7, k = u & 127;
        Btf1[(size_t)n * 128 + k] = f2h(f1[(size_t)k * 256 + n]);
    } else if (t < 81920) {          // ffn2: I=256, O=128
        int u = t - 49152;
        int n = u >> 8, k = u & 255;
        Btf2[(size_t)n * 256 + k] = f2h(f2[(size_t)k * 128 + n]);
    }
}

// ----------------------------------------- per-relation gathered sums -> Ab rows (fp16, 1152)
// half2 packed accumulation; 4-edge unroll (r9); relation derived from rstart (r12).
__global__ __launch_bounds__(256)
void s_pass(const ushort* __restrict__ hnhf, const int* __restrict__ ssrc,
            const int* __restrict__ rstart, ushort* __restrict__ Ab, int c0, int c1) {
    int n = c0 + ((blockIdx.x * 256 + threadIdx.x) >> 6);
    if (n >= c1) return;
    int lane = threadIdx.x & 63;
    const int* rp = rstart + n * REL;
    int e0 = rp[0];
    int rs1 = rp[1], rs2 = rp[2], rs3 = rp[3], rs4 = rp[4];
    int rs5 = rp[5], rs6 = rp[6], rs7 = rp[7], rs8 = rp[8];
    int e1 = rp[9];
    h16x2 a0 = (h16x2)0, a1 = (h16x2)0, a2 = (h16x2)0, a3 = (h16x2)0, a4 = (h16x2)0;
    h16x2 a5 = (h16x2)0, a6 = (h16x2)0, a7 = (h16x2)0, a8 = (h16x2)0;
#define RELOF(ee) (((ee) >= rs1) + ((ee) >= rs2) + ((ee) >= rs3) + ((ee) >= rs4) + \
                   ((ee) >= rs5) + ((ee) >= rs6) + ((ee) >= rs7) + ((ee) >= rs8))
#define ACC(rr, hv) switch (rr) { \
        case 0: a0 += hv; break; case 1: a1 += hv; break; case 2: a2 += hv; break; \
        case 3: a3 += hv; break; case 4: a4 += hv; break; case 5: a5 += hv; break; \
        case 6: a6 += hv; break; case 7: a7 += hv; break; default: a8 += hv; break; }
    int e = e0;
    for (; e + 4 <= e1; e += 4) {
        int s0 = ssrc[e], s1 = ssrc[e + 1], s2 = ssrc[e + 2], s3 = ssrc[e + 3];
        int r0 = RELOF(e), r1 = RELOF(e + 1), r2 = RELOF(e + 2), r3 = RELOF(e + 3);
        h16x2 hv0 = *(const h16x2*)&hnhf[(size_t)s0 * D + 2 * lane];
        h16x2 hv1 = *(const h16x2*)&hnhf[(size_t)s1 * D + 2 * lane];
        h16x2 hv2 = *(const h16x2*)&hnhf[(size_t)s2 * D + 2 * lane];
        h16x2 hv3 = *(const h16x2*)&hnhf[(size_t)s3 * D + 2 * lane];
        ACC(r0, hv0)
        ACC(r1, hv1)
        ACC(r2, hv2)
        ACC(r3, hv3)
    }
    for (; e < e1; ++e) {
        int s0 = ssrc[e];
        int r0 = RELOF(e);
        h16x2 hv0 = *(const h16x2*)&hnhf[(size_t)s0 * D + 2 * lane];
        ACC(r0, hv0)
    }
#undef ACC
#undef RELOF
    ushort* arow = Ab + (size_t)(n - c0) * 1152;
#define ST(r) *(h16x2*)&arow[r * 128 + 2 * lane] = a##r;
    ST(0) ST(1) ST(2) ST(3) ST(4) ST(5) ST(6) ST(7) ST(8)
#undef ST
}

// ---------------------------------------------------- QKV MFMA GEMM, full 384-col block
// Block = 128 rows x ALL 384 cols (A read ONCE).
// 512 threads, 8 waves (2 row-halves x 4 col-quarters), acc[4][6]; LDS 64 KB (2 blk/CU).
// K: 0..127 from hnhf (lda 128), 128..1279 from Ab (lda 1152, col k-128).
__global__ __launch_bounds__(512)
void mfma_gemm384(const ushort* __restrict__ A1, const ushort* __restrict__ Ab, int M,
                  const ushort* __restrict__ Bt, const float* __restrict__ bias,
                  ushort* __restrict__ Cout) {
    __shared__ ushort As[128 * 64];
    __shared__ ushort Bs[384 * 64];
    const int tid = threadIdx.x;
    const int lane = tid & 63;
    const int wave = tid >> 6;               // 0..7
    const int wm = wave & 1, wn = wave >> 1; // 2 row-halves x 4 col-quarters
    const int quad = lane >> 4, l16 = lane & 15;
    const int row0 = blockIdx.x * 128;

    const ushort* sA1[2];
    const ushort* sA2[2];
#pragma unroll
    for (int i = 0; i < 2; ++i) {
        int rs = (wave * 2 + i) * 8 + (lane >> 3);
        int kg = (lane & 7) ^ (rs & 7);
        int ra = row0 + rs; if (ra >= M) ra = M - 1;
        sA1[i] = A1 + (size_t)ra * 128 + kg * 8;
        sA2[i] = Ab + (size_t)ra * 1152 + kg * 8;
    }
    const ushort* sB[6];
#pragma unroll
    for (int i = 0; i < 6; ++i) {
        int rs = (wave * 6 + i) * 8 + (lane >> 3);
        int kg = (lane & 7) ^ (rs & 7);
        sB[i] = Bt + (size_t)rs * 1280 + kg * 8;
    }

    f32x4 acc[4][6];
#pragma unroll
    for (int i = 0; i < 4; ++i)
#pragma unroll
        for (int j = 0; j < 6; ++j) acc[i][j] = (f32x4){0.f, 0.f, 0.f, 0.f};

    for (int kc = 0; kc < 1280; kc += 64) {
#pragma unroll
        for (int i = 0; i < 6; ++i) ld16(sB[i] + kc, &Bs[(wave * 6 + i) * 512]);
#pragma unroll
        for (int i = 0; i < 2; ++i) {
            const ushort* as = (kc < 128) ? (sA1[i] + kc) : (sA2[i] + (kc - 128));
            ld16(as, &As[(wave * 2 + i) * 512]);
        }
        __syncthreads();
#pragma unroll
        for (int h = 0; h < 2; ++h) {
            f16x8 af[4], bf[6];
#pragma unroll
            for (int i = 0; i < 4; ++i) {
                int r = wm * 64 + i * 16 + l16;
                af[i] = *(const f16x8*)&As[r * 64 + (((h * 4 + quad) ^ (r & 7)) * 8)];
            }
#pragma unroll
            for (int j = 0; j < 6; ++j) {
                int c = wn * 96 + j * 16 + l16;
                bf[j] = *(const f16x8*)&Bs[c * 64 + (((h * 4 + quad) ^ (c & 7)) * 8)];
            }
#pragma unroll
            for (int i = 0; i < 4; ++i)
#pragma unroll
                for (int j = 0; j < 6; ++j)
                    acc[i][j] = __builtin_amdgcn_mfma_f32_16x16x32_f16(af[i], bf[j], acc[i][j], 0, 0, 0);
        }
        __syncthreads();
    }

#pragma unroll
    for (int i = 0; i < 4; ++i) {
        int gr0 = wm * 64 + i * 16 + quad * 4 + row0;
#pragma unroll
        for (int r = 0; r < 4; ++r) {
            int gr = gr0 + r;
            if (gr >= M) continue;
#pragma unroll
            for (int j = 0; j < 6; ++j) {
                int gcol = wn * 96 + j * 16 + l16;
                float v = acc[i][j][r] + bias[gcol];
                v = fmaxf(v, 0.f);
                Cout[(size_t)gr * 384 + gcol] = f2h(v);
            }
        }
    }
}

// -------------------- o-projection + fused row LayerNorm + fused gn2 STATS (round 13)
// mfma_gemm_ln with the gn2 Σx/Σx² accumulated from the epilogue registers (round-8
// reduction shape: predicated per-group partials -> shfl quad-reduce -> [2][128] LDS
// -> ONE atomicAdd pair per (group, channel, block)). Stats use the fp16-rounded value
// so the math is bit-identical to the deleted gn_stats_h. 256 threads, 4 waves.
__global__ __launch_bounds__(256, 3)
void mfma_gemm_ln_gn(const ushort* __restrict__ A, int lda, int M,
                     const ushort* __restrict__ Bt, int K,
                     const float* __restrict__ bias, const float* __restrict__ lng,
                     const float* __restrict__ lnb, ushort* __restrict__ Cout,
                     const int* __restrict__ seg, float* __restrict__ g2sum,
                     float* __restrict__ g2sumsq) {
    __shared__ ushort As[128 * 64];
    __shared__ ushort Bs[128 * 64];
    __shared__ float rsum[2][128];
    __shared__ float rsq[2][128];
    __shared__ float sbuf[2][128];
    __shared__ float qbuf[2][128];
    const int tid = threadIdx.x;
    const int lane = tid & 63;
    const int wave = tid >> 6;
    const int wm = wave & 1, wn = wave >> 1;
    const int quad = lane >> 4, l16 = lane & 15;
    const int row0 = blockIdx.y * 128;

    const ushort* sA[4];
    const ushort* sB[4];
#pragma unroll
    for (int i = 0; i < 4; ++i) {
        int rs = (wave * 4 + i) * 8 + (lane >> 3);
        int kg = (lane & 7) ^ (rs & 7);
        int ra = row0 + rs; if (ra >= M) ra = M - 1;
        sA[i] = A + (size_t)ra * lda + kg * 8;
        sB[i] = Bt + (size_t)rs * K + kg * 8;
    }

    f32x4 acc[4][4];
#pragma unroll
    for (int i = 0; i < 4; ++i)
#pragma unroll
        for (int j = 0; j < 4; ++j) acc[i][j] = (f32x4){0.f, 0.f, 0.f, 0.f};

    for (int kc = 0; kc < K; kc += 64) {
#pragma unroll
        for (int i = 0; i < 4; ++i) {
            ld16(sA[i] + kc, &As[(wave * 4 + i) * 512]);
            ld16(sB[i] + kc, &Bs[(wave * 4 + i) * 512]);
        }
        __syncthreads();
#pragma unroll
        for (int h = 0; h < 2; ++h) {
            f16x8 af[4], bf[4];
#pragma unroll
            for (int i = 0; i < 4; ++i) {
                int r = wm * 64 + i * 16 + l16;
                af[i] = *(const f16x8*)&As[r * 64 + (((h * 4 + quad) ^ (r & 7)) * 8)];
                int c = wn * 64 + i * 16 + l16;
                bf[i] = *(const f16x8*)&Bs[c * 64 + (((h * 4 + quad) ^ (c & 7)) * 8)];
            }
#pragma unroll
            for (int i = 0; i < 4; ++i)
#pragma unroll
                for (int j = 0; j < 4; ++j)
                    acc[i][j] = __builtin_amdgcn_mfma_f32_16x16x32_f16(af[i], bf[j], acc[i][j], 0, 0, 0);
        }
        __syncthreads();
    }

    // row sums for LN
#pragma unroll
    for (int i = 0; i < 4; ++i) {
#pragma unroll
        for (int r = 0; r < 4; ++r) {
            float s = 0.f, q = 0.f;
#pragma unroll
            for (int j = 0; j < 4; ++j) {
                float v = acc[i][j][r] + bias[wn * 64 + j * 16 + l16];
                s += v; q += v * v;
            }
            s += __shfl_xor(s, 1); q += __shfl_xor(q, 1);
            s += __shfl_xor(s, 2); q += __shfl_xor(q, 2);
            s += __shfl_xor(s, 4); q += __shfl_xor(q, 4);
            s += __shfl_xor(s, 8); q += __shfl_xor(q, 8);
            if (l16 == 0) {
                int row = wm * 64 + i * 16 + quad * 4 + r;
                rsum[wn][row] = s;
                rsq[wn][row] = q;
            }
        }
    }
    __syncthreads();

    // LN write
#pragma unroll
    for (int i = 0; i < 4; ++i) {
#pragma unroll
        for (int r = 0; r < 4; ++r) {
            int row = wm * 64 + i * 16 + quad * 4 + r;
            int grow = row0 + row;
            if (grow >= M) continue;
            float tot = rsum[0][row] + rsum[1][row];
            float tq  = rsq[0][row] + rsq[1][row];
            float mu = tot * (1.f / 128.f);
            float var = tq * (1.f / 128.f) - mu * mu;
            float rstd = rsqrtf(var + 1e-5f);
#pragma unroll
            for (int j = 0; j < 4; ++j) {
                int gcol = wn * 64 + j * 16 + l16;
                float v = acc[i][j][r] + bias[gcol];
                float o = lng[gcol] * (v - mu) * rstd + lnb[gcol];
                Cout[(size_t)grow * 128 + gcol] = f2h(o);
            }
        }
    }

    // fused gn2 stats: per-group predicated partials over this block's rows
    int gfirst = seg[min(row0, M - 1)];
    int glast = seg[min(row0 + 127, M - 1)];
    for (int g = gfirst; g <= glast; ++g) {
        float sA4[4] = {0.f, 0.f, 0.f, 0.f};
        float qA4[4] = {0.f, 0.f, 0.f, 0.f};
#pragma unroll
        for (int i = 0; i < 4; ++i) {
#pragma unroll
            for (int r = 0; r < 4; ++r) {
                int row = wm * 64 + i * 16 + quad * 4 + r;
                int grow = row0 + row;
                bool ok = (grow < M) && (seg[min(grow, M - 1)] == g);
                float tot = rsum[0][row] + rsum[1][row];
                float tq  = rsq[0][row] + rsq[1][row];
                float mu = tot * (1.f / 128.f);
                float var = tq * (1.f / 128.f) - mu * mu;
                float rstd = rsqrtf(var + 1e-5f);
#pragma unroll
                for (int j = 0; j < 4; ++j) {
                    int gcol = wn * 64 + j * 16 + l16;
                    float v = acc[i][j][r] + bias[gcol];
                    float o = lng[gcol] * (v - mu) * rstd + lnb[gcol];
                    float orr = h2f(f2h(o));   // fp16-rounded, bit-identical to gn_stats_h input
                    if (ok) { sA4[j] += orr; qA4[j] += orr * orr; }
                }
            }
        }
        // reduce over quad (lane bits 4,5)
#pragma unroll
        for (int j = 0; j < 4; ++j) {
            sA4[j] += __shfl_xor(sA4[j], 16); qA4[j] += __shfl_xor(qA4[j], 16);
            sA4[j] += __shfl_xor(sA4[j], 32); qA4[j] += __shfl_xor(qA4[j], 32);
        }
        if (quad == 0) {
#pragma unroll
            for (int j = 0; j < 4; ++j) {
                int col = wn * 64 + j * 16 + l16;
                sbuf[wm][col] = sA4[j];
                qbuf[wm][col] = qA4[j];
            }
        }
        __syncthreads();
        if (tid < 128) {
            atomicAdd(&g2sum[g * D + tid], sbuf[0][tid] + sbuf[1][tid]);
            atomicAdd(&g2sumsq[g * D + tid], qbuf[0][tid] + qbuf[1][tid]);
        }
        __syncthreads();
    }
}

// ---------------------------------------------------------------- fused FFN v3 (r12 proven)
// 64-row blocks, 75 KB LDS (2 blk/CU), padded row-major C1s; gn2-apply fused on the
// reg-staged A path (bit-identical math to the old gn_apply_h).
__global__ __launch_bounds__(512)
void ffn_fused(const ushort* __restrict__ h1, const int* __restrict__ seg,
               const float* __restrict__ gsc, const float* __restrict__ goff, int M,
               const ushort* __restrict__ B1t, const float* __restrict__ b1,
               const ushort* __restrict__ B2t, const float* __restrict__ b2,
               const float* __restrict__ lng, const float* __restrict__ lnb,
               float* __restrict__ Cout) {
    extern __shared__ ushort sh[];
    ushort* As   = sh;                           // 64*64   =  8 KB
    ushort* Bs   = sh + 64 * 64;                 // 256*64  = 32 KB (phase1) / 128*64 (phase2)
    ushort* C1s  = sh + 64 * 64 + 256 * 64;      // 64*264  = 33 KB
    float*  rsum = (float*)(C1s + 64 * C1LD);    // [4][64]
    float*  rsq  = rsum + 4 * 64;
    const int tid = threadIdx.x;
    const int lane = tid & 63;
    const int wave = tid >> 6;               // 0..7
    const int wm = wave & 1, wn = wave >> 1; // 2 row-halves(32) x 4 col groups
    const int quad = lane >> 4, l16 = lane & 15;
    const int row0 = blockIdx.x * 64;

    // ---------------- phase 1: C1 = relu(gn2(h1) x B1t + b1), 64x256, K=128
    {
        int rsA = wave * 8 + (lane >> 3);
        int kgA = (lane & 7) ^ (rsA & 7);
        int raA = row0 + rsA; if (raA >= M) raA = M - 1;
        int gA = seg[raA];
        const ushort* srcA = h1 + (size_t)raA * 128 + kgA * 8;
        const float*  scp  = gsc + gA * 128 + kgA * 8;
        const float*  offp = goff + gA * 128 + kgA * 8;
        ushort* dstA = &As[wave * 512 + lane * 8];   // = ld16's dest (base + lane*16 B)
        const ushort* sB[4];
#pragma unroll
        for (int i = 0; i < 4; ++i) {
            int rs = (wave * 4 + i) * 8 + (lane >> 3);
            int kg = (lane & 7) ^ (rs & 7);
            sB[i] = B1t + (size_t)rs * 128 + kg * 8;
        }
        f32x4 acc[2][4];
#pragma unroll
        for (int i = 0; i < 2; ++i)
#pragma unroll
            for (int j = 0; j < 4; ++j) acc[i][j] = (f32x4){0.f, 0.f, 0.f, 0.f};

        for (int kc = 0; kc < 128; kc += 64) {
#pragma unroll
            for (int i = 0; i < 4; ++i) ld16(sB[i] + kc, &Bs[(wave * 4 + i) * 512]);
            // reg-staged A with fused gn2-apply
            {
                ushort4 u0 = *(const ushort4*)(srcA + kc);
                ushort4 u1 = *(const ushort4*)(srcA + kc + 4);
                float4 sc0 = *(const float4*)(scp + kc);
                float4 sc1 = *(const float4*)(scp + kc + 4);
                float4 of0 = *(const float4*)(offp + kc);
                float4 of1 = *(const float4*)(offp + kc + 4);
                f16x8 av;
                av[0] = (_Float16)(sc0.x * h2f(u0.x) + of0.x);
                av[1] = (_Float16)(sc0.y * h2f(u0.y) + of0.y);
                av[2] = (_Float16)(sc0.z * h2f(u0.z) + of0.z);
                av[3] = (_Float16)(sc0.w * h2f(u0.w) + of0.w);
                av[4] = (_Float16)(sc1.x * h2f(u1.x) + of1.x);
                av[5] = (_Float16)(sc1.y * h2f(u1.y) + of1.y);
                av[6] = (_Float16)(sc1.z * h2f(u1.z) + of1.z);
                av[7] = (_Float16)(sc1.w * h2f(u1.w) + of1.w);
                *(f16x8*)dstA = av;
            }
            __syncthreads();
#pragma unroll
            for (int h = 0; h < 2; ++h) {
                f16x8 af[2], bf[4];
#pragma unroll
                for (int i = 0; i < 2; ++i) {
                    int r = wm * 32 + i * 16 + l16;
                    af[i] = *(const f16x8*)&As[r * 64 + (((h * 4 + quad) ^ (r & 7)) * 8)];
                }
#pragma unroll
                for (int j = 0; j < 4; ++j) {
                    int c = wn * 64 + j * 16 + l16;
                    bf[j] = *(const f16x8*)&Bs[c * 64 + (((h * 4 + quad) ^ (c & 7)) * 8)];
                }
#pragma unroll
                for (int i = 0; i < 2; ++i)
#pragma unroll
                    for (int j = 0; j < 4; ++j)
                        acc[i][j] = __builtin_amdgcn_mfma_f32_16x16x32_f16(af[i], bf[j], acc[i][j], 0, 0, 0);
            }
            __syncthreads();
        }

        // epilogue: relu + bias -> C1s (row-major, +8 pad); conflict-free stores.
#pragma unroll
        for (int i = 0; i < 2; ++i) {
            int lr0 = wm * 32 + i * 16 + quad * 4;
#pragma unroll
            for (int r = 0; r < 4; ++r) {
                int row = lr0 + r;
#pragma unroll
                for (int j = 0; j < 4; ++j) {
                    int col = wn * 64 + j * 16 + l16;
                    float v = acc[i][j][r] + b1[col];
                    v = fmaxf(v, 0.f);
                    C1s[row * C1LD + col] = f2h(v);
                }
            }
        }
    }
    __syncthreads();

    // ---------------- phase 2: C2 = C1 x B2t + b2 (+row-LN), 64x128, K=256
    {
        const ushort* sB[2];
#pragma unroll
        for (int i = 0; i < 2; ++i) {
            int rs = (wave * 2 + i) * 8 + (lane >> 3);
            int kg = (lane & 7) ^ (rs & 7);
            sB[i] = B2t + (size_t)rs * 256 + kg * 8;
        }
        f32x4 acc[2][2];
#pragma unroll
        for (int i = 0; i < 2; ++i)
#pragma unroll
            for (int j = 0; j < 2; ++j) acc[i][j] = (f32x4){0.f, 0.f, 0.f, 0.f};

        for (int kc = 0; kc < 256; kc += 64) {
#pragma unroll
            for (int i = 0; i < 2; ++i) ld16(sB[i] + kc, &Bs[(wave * 2 + i) * 512]);
            __syncthreads();
#pragma unroll
            for (int h = 0; h < 2; ++h) {
                f16x8 af[2], bf[2];
#pragma unroll
                for (int i = 0; i < 2; ++i) {
                    int r = wm * 32 + i * 16 + l16;
                    af[i] = *(const f16x8*)&C1s[r * C1LD + kc + ((h * 4 + quad) * 8)];
                }
#pragma unroll
                for (int j = 0; j < 2; ++j) {
                    int c = wn * 32 + j * 16 + l16;
                    bf[j] = *(const f16x8*)&Bs[c * 64 + (((h * 4 + quad) ^ (c & 7)) * 8)];
                }
#pragma unroll
                for (int i = 0; i < 2; ++i)
#pragma unroll
                    for (int j = 0; j < 2; ++j)
                        acc[i][j] = __builtin_amdgcn_mfma_f32_16x16x32_f16(af[i], bf[j], acc[i][j], 0, 0, 0);
            }
            __syncthreads();
        }

        // row-LN across the 4 col groups
#pragma unroll
        for (int i = 0; i < 2; ++i) {
#pragma unroll
            for (int r = 0; r < 4; ++r) {
                float s = 0.f, q = 0.f;
#pragma unroll
                for (int j = 0; j < 2; ++j) {
                    float v = acc[i][j][r] + b2[wn * 32 + j * 16 + l16];
                    s += v; q += v * v;
                }
                s += __shfl_xor(s, 1); q += __shfl_xor(q, 1);
                s += __shfl_xor(s, 2); q += __shfl_xor(q, 2);
                s += __shfl_xor(s, 4); q += __shfl_xor(q, 4);
                s += __shfl_xor(s, 8); q += __shfl_xor(q, 8);
                if (l16 == 0) {
                    int row = wm * 32 + i * 16 + quad * 4 + r;
                    rsum[wn * 64 + row] = s;
                    rsq[wn * 64 + row] = q;
                }
            }
        }
        __syncthreads();

#pragma unroll
        for (int i = 0; i < 2; ++i) {
#pragma unroll
            for (int r = 0; r < 4; ++r) {
                int row = wm * 32 + i * 16 + quad * 4 + r;
                int grow = row0 + row;
                if (grow >= M) continue;
                float tot = rsum[row] + rsum[64 + row] + rsum[128 + row] + rsum[192 + row];
                float tq  = rsq[row] + rsq[64 + row] + rsq[128 + row] + rsq[192 + row];
                float mu = tot * (1.f / 128.f);
                float var = tq * (1.f / 128.f) - mu * mu;
                float rstd = rsqrtf(var + 1e-5f);
#pragma unroll
                for (int j = 0; j < 2; ++j) {
                    int gcol = wn * 32 + j * 16 + l16;
                    float v = acc[i][j][r] + b2[gcol];
                    float o = lng[gcol] * (v - mu) * rstd + lnb[gcol];
                    Cout[(size_t)grow * 128 + gcol] = o;
                }
            }
        }
    }
}

// --------------------------------------------------------------- attention
// 8-edge unroll (proven r9); at gather-BW plateau (~3.5 TB/s) — don't touch.
__global__ __launch_bounds__(256)
void attn_kernel(const ushort* __restrict__ C, const int* __restrict__ ssrc,
                 const int* __restrict__ rstart, ushort* __restrict__ attnhf) {
    int n = (blockIdx.x * 256 + threadIdx.x) >> 6;
    if (n >= N_NODES) return;
    int lane = threadIdx.x & 63;
    h16x2 qh = *(const h16x2*)&C[(size_t)n * 384 + 2 * lane];
    int e0 = rstart[n * REL], e1 = rstart[n * REL + REL];
    float wvx = 0.f, wvy = 0.f, z = 0.f;
    int e = e0;
    for (; e + 8 <= e1; e += 8) {
        int s[8];
#pragma unroll
        for (int j = 0; j < 8; ++j) s[j] = ssrc[e + j];
        h16x2 kk[8], vv[8];
#pragma unroll
        for (int j = 0; j < 8; ++j) kk[j] = *(const h16x2*)&C[(size_t)s[j] * 384 + 128 + 2 * lane];
#pragma unroll
        for (int j = 0; j < 8; ++j) vv[j] = *(const h16x2*)&C[(size_t)s[j] * 384 + 256 + 2 * lane];
        float d[8];
#pragma unroll
        for (int j = 0; j < 8; ++j) d[j] = __builtin_amdgcn_fdot2(kk[j], qh, 0.f, false);
#pragma unroll
        for (int j = 0; j < 8; ++j) d[j] += __shfl_xor(d[j], 1);
#pragma unroll
        for (int j = 0; j < 8; ++j) d[j] += __shfl_xor(d[j], 2);
#pragma unroll
        for (int j = 0; j < 8; ++j) d[j] += __shfl_xor(d[j], 4);
#pragma unroll
        for (int j = 0; j < 8; ++j) {
            float sc = __expf(fminf(fmaxf(d[j] * 0.25f, -10.f), 10.f));
            wvx += sc * (float)vv[j].x;
            wvy += sc * (float)vv[j].y;
            z += sc;
        }
    }
    for (; e + 4 <= e1; e += 4) {
        int s0 = ssrc[e], s1 = ssrc[e + 1], s2 = ssrc[e + 2], s3 = ssrc[e + 3];
        h16x2 k0 = *(const h16x2*)&C[(size_t)s0 * 384 + 128 + 2 * lane];
        h16x2 k1 = *(const h16x2*)&C[(size_t)s1 * 384 + 128 + 2 * lane];
        h16x2 k2 = *(const h16x2*)&C[(size_t)s2 * 384 + 128 + 2 * lane];
        h16x2 k3 = *(const h16x2*)&C[(size_t)s3 * 384 + 128 + 2 * lane];
        h16x2 v0 = *(const h16x2*)&C[(size_t)s0 * 384 + 256 + 2 * lane];
        h16x2 v1 = *(const h16x2*)&C[(size_t)s1 * 384 + 256 + 2 * lane];
        h16x2 v2 = *(const h16x2*)&C[(size_t)s2 * 384 + 256 + 2 * lane];
        h16x2 v3 = *(const h16x2*)&C[(size_t)s3 * 384 + 256 + 2 * lane];
        float d0 = __builtin_amdgcn_fdot2(k0, qh, 0.f, false);
        float d1 = __builtin_amdgcn_fdot2(k1, qh, 0.f, false);
        float d2 = __builtin_amdgcn_fdot2(k2, qh, 0.f, false);
        float d3 = __builtin_amdgcn_fdot2(k3, qh, 0.f, false);
        d0 += __shfl_xor(d0, 1); d1 += __shfl_xor(d1, 1);
        d2 += __shfl_xor(d2, 1); d3 += __shfl_xor(d3, 1);
        d0 += __shfl_xor(d0, 2); d1 += __shfl_xor(d1, 2);
        d2 += __shfl_xor(d2, 2); d3 += __shfl_xor(d3, 2);
        d0 += __shfl_xor(d0, 4); d1 += __shfl_xor(d1, 4);
        d2 += __shfl_xor(d2, 4); d3 += __shfl_xor(d3, 4);
        float sc0 = __expf(fminf(fmaxf(d0 * 0.25f, -10.f), 10.f));
        float sc1 = __expf(fminf(fmaxf(d1 * 0.25f, -10.f), 10.f));
        float sc2 = __expf(fminf(fmaxf(d2 * 0.25f, -10.f), 10.f));
        float sc3 = __expf(fminf(fmaxf(d3 * 0.25f, -10.f), 10.f));
        wvx += sc0 * (float)v0.x + sc1 * (float)v1.x;
        wvy += sc0 * (float)v0.y + sc1 * (float)v1.y;
        wvx += sc2 * (float)v2.x + sc3 * (float)v3.x;
        wvy += sc2 * (float)v2.y + sc3 * (float)v3.y;
        z += sc0 + sc1 + sc2 + sc3;
    }
    for (; e < e1; ++e) {
        int s0 = ssrc[e];
        h16x2 k0 = *(const h16x2*)&C[(size_t)s0 * 384 + 128 + 2 * lane];
        h16x2 v0 = *(const h16x2*)&C[(size_t)s0 * 384 + 256 + 2 * lane];
        float d0 = __builtin_amdgcn_fdot2(k0, qh, 0.f, false);
        d0 += __shfl_xor(d0, 1);
        d0 += __shfl_xor(d0, 2);
        d0 += __shfl_xor(d0, 4);
        float sc0 = __expf(fminf(fmaxf(d0 * 0.25f, -10.f), 10.f));
        wvx += sc0 * (float)v0.x;
        wvy += sc0 * (float)v0.y;
        z += sc0;
    }
    float inv = 1.f / (z + 1e-6f);
    ushort2 o;
    o.x = f2h(wvx * inv);
    o.y = f2h(wvy * inv);
    *(ushort2*)&attnhf[(size_t)n * D + 2 * lane] = o;
}

// ------------------------------------------------------------------ launch
extern "C" void kernel_launch(void* const* d_in, const int* in_sizes, int n_in,
                              void* d_out, int out_size, void* d_ws, size_t ws_size,
                              hipStream_t stream) {
    (void)in_sizes; (void)n_in; (void)out_size;
    const float* h     = (const float*)d_in[0];
    const int*   src   = (const int*)d_in[1];
    const int*   dst   = (const int*)d_in[2];
    const int*   ety   = (const int*)d_in[3];
    const int*   seg   = (const int*)d_in[4];
    const float* coeffs[3] = {(const float*)d_in[6],  (const float*)d_in[10], (const float*)d_in[14]};
    const float* bases [3] = {(const float*)d_in[7],  (const float*)d_in[11], (const float*)d_in[15]};
    const float* loops [3] = {(const float*)d_in[8],  (const float*)d_in[12], (const float*)d_in[16]};
    const float* pbias [3] = {(const float*)d_in[9],  (const float*)d_in[13], (const float*)d_in[17]};
    const float* o_w   = (const float*)d_in[18];
    const float* o_b   = (const float*)d_in[19];
    const float* gn1_w = (const float*)d_in[20];
    const float* gn1_b = (const float*)d_in[21];
    const float* gn1_ms= (const float*)d_in[22];
    const float* gn2_w = (const float*)d_in[23];
    const float* gn2_b = (const float*)d_in[24];
    const float* gn2_ms= (const float*)d_in[25];
    const float* ln1_g = (const float*)d_in[26];
    const float* ln1_b = (const float*)d_in[27];
    const float* ln2_g = (const float*)d_in[28];
    const float* ln2_b = (const float*)d_in[29];
    const float* ffn1_w= (const float*)d_in[30];
    const float* ffn1_b= (const float*)d_in[31];
    const float* ffn2_w= (const float*)d_in[32];
    const float* ffn2_b= (const float*)d_in[33];

    char* p = (char*)d_ws;
    auto take = [&](size_t bytes) { char* r = p; p += (bytes + 255) & ~(size_t)255; return r; };
    int*    cnt9   = (int*)take((size_t)NK9 * 2 * 4);   // cnt9 + cur9, single memset
    int*    cur9   = cnt9 + NK9;
    int*    rstart = (int*)take((size_t)(NK9 + 8) * 4); // +sentinel
    int*    bsum   = (int*)take(512);
    int*    ssrc   = (int*)take((size_t)N_EDGES * 4);
    float*  gsum   = (float*)take((size_t)NG * D * 4 * 2);
    float*  gsumsq = gsum + NG * D;
    float*  gsc    = (float*)take((size_t)NG * D * 4);
    float*  goff   = (float*)take((size_t)NG * D * 4);
    ushort* Btqkv  = (ushort*)take((size_t)384 * 1280 * 2);
    float*  biasq  = (float*)take(384 * 4);
    ushort* Bto    = (ushort*)take((size_t)128 * 128 * 2);
    ushort* Btf1   = (ushort*)take((size_t)256 * 128 * 2);
    ushort* Btf2   = (ushort*)take((size_t)128 * 256 * 2);
    ushort* hnhf   = (ushort*)take((size_t)N_NODES * D * 2);     // 25.6 MB
    ushort* attnhf = (ushort*)take((size_t)N_NODES * D * 2);     // 25.6 MB
    ushort* h1hf   = (ushort*)take((size_t)N_NODES * D * 2);     // 25.6 MB
    ushort* Cqkv   = (ushort*)take((size_t)N_NODES * 384 * 2);   // 76.8 MB
    size_t used = (size_t)(p - (char*)d_ws);
    size_t avail = (ws_size > used) ? ws_size - used : 0;
    int NC = 1;
    if (avail < (size_t)N_NODES * 1152 * 2) NC = 4;
    if (NC == 4 && avail < ((size_t)(N_NODES / 4 + 1) * 1152 * 2)) NC = 8;
    ushort* Ab = (ushort*)p;
    const int chunk = (N_NODES + NC - 1) / NC;

    const int EB = (N_EDGES + 255) / 256;
    const int KB = (NK9 + 8191) / 8192;               // 110 blocks <= scan2's 128
    const int WB = (N_NODES * 64 + 255) / 256;
    const int GB = (N_NODES + 127) / 128;
    const int RB = (N_NODES + 127) / 128;
    const int FB = (N_NODES + 63) / 64;

    // ---- sort edges by (dst, etype)
    hipMemsetAsync(cnt9, 0, (size_t)NK9 * 8, stream);  // cnt9 + cur9
    hist9_kernel<<<EB, 256, 0, stream>>>(dst, ety, cnt9);
    scan1_8<<<KB, 1024, 0, stream>>>(cnt9, rstart, bsum, NK9);
    scan2_kernel<<<1, 128, 0, stream>>>(bsum, KB);
    scan3_8<<<KB, 1024, 0, stream>>>(rstart, bsum, NK9, N_EDGES);
    scatter9_kernel<<<EB, 256, 0, stream>>>(src, dst, ety, rstart, cur9, ssrc);

    // ---- weights (2 dispatches total)
    build_bt_qkv3<<<dim3(640, 3), 256, 0, stream>>>(
        coeffs[0], coeffs[1], coeffs[2], bases[0], bases[1], bases[2],
        loops[0], loops[1], loops[2], pbias[0], pbias[1], pbias[2], Btqkv, biasq);
    transpose_cast3<<<320, 256, 0, stream>>>(o_w, Bto, ffn1_w, Btf1, ffn2_w, Btf2);

    // ---- graph norm 1 -> hnhf (fp16)
    hipMemsetAsync(gsum, 0, (size_t)NG * D * 8, stream);
    gn_stats<<<GB, 256, 0, stream>>>(h, seg, gsum, gsumsq);
    gn_final<<<NG, 128, 0, stream>>>(gsum, gsumsq, seg, gn1_w, gn1_b, gn1_ms, gsc, goff);
    gn_apply<<<WB, 256, 0, stream>>>(h, seg, gsc, goff, hnhf);

    // ---- QKV: S-pass + full-width (384-col) MFMA GEMM per chunk -> Cqkv (fp16)
    for (int c = 0; c < NC; ++c) {
        int c0 = c * chunk;
        int c1 = min(N_NODES, c0 + chunk);
        int rows = c1 - c0;
        if (rows <= 0) break;
        s_pass<<<(rows + 3) / 4, 256, 0, stream>>>(hnhf, ssrc, rstart, Ab, c0, c1);
        mfma_gemm384<<<(rows + 127) / 128, 512, 0, stream>>>(
            hnhf + (size_t)c0 * 128, Ab, rows, Btqkv, biasq, Cqkv + (size_t)c0 * 384);
    }

    // ---- attention -> attnhf (fp16); Cqkv dead after this
    attn_kernel<<<WB, 256, 0, stream>>>(Cqkv, ssrc, rstart, attnhf);

    // ---- gn2 stats buffer must be zero BEFORE the fused o-proj kernel
    hipMemsetAsync(gsum, 0, (size_t)NG * D * 8, stream);

    // ---- output projection + fused ln1 + fused gn2 STATS -> h1hf (fp16) + gsum/gsumsq
    mfma_gemm_ln_gn<<<dim3(1, RB), 256, 0, stream>>>(
        attnhf, 128, N_NODES, Bto, 128, o_b, ln1_g, ln1_b, h1hf, seg, gsum, gsumsq);

    // ---- gn2 final (apply is fused into ffn_fused's A staging)
    gn_final<<<NG, 128, 0, stream>>>(gsum, gsumsq, seg, gn2_w, gn2_b, gn2_ms, gsc, goff);

    // ---- fused FFN v3: relu(gn2(h1) x W1 + b1) x W2 + b2, + ln2 -> d_out (fp32)
    const int FFN_LDS = (64 * 64 + 256 * 64 + 64 * C1LD) * 2 + 2 * 4 * 64 * 4;  // 76800
    hipFuncSetAttribute((const void*)ffn_fused, hipFuncAttributeMaxDynamicSharedMemorySize, FFN_LDS);
    ffn_fused<<<FB, 512, FFN_LDS, stream>>>(
        h1hf, seg, gsc, goff, N_NODES, Btf1, ffn1_b, Btf2, ffn2_b, ln2_g, ln2_b, (float*)d_out);
}